// Round 3
// baseline (1067.697 us; speedup 1.0000x reference)
//
#include <hip/hip_runtime.h>
#include <hip/hip_bf16.h>
#include <cstdint>

// ---------------------------------------------------------------------------
// SiameseGNN. R3: channel-sliced XCD-pinned aggregation. z/h/o1 stored
// slice-major [8][N1][SW] so each XCD's gather working set (3.25MB) fits its
// 4MB L2. Edge meta packed to {src, ew*dinv[src]} in CSR order (8B/edge).
// Parallel 3-kernel scan; wave-shfl topk.
// ---------------------------------------------------------------------------

// ---------------- init: deg1=1.0 (self loop), cnt=0, cur=0 -----------------
__global__ void init1_kernel(float* deg, int* cnt, int* cur, int n) {
    int i = blockIdx.x * 256 + threadIdx.x;
    if (i < n) { deg[i] = 1.0f; cnt[i] = 0; cur[i] = 0; }
}

__global__ void hist_kernel(const int* __restrict__ dst, const float* __restrict__ ew,
                            float* deg, int* cnt, int E) {
    int e = blockIdx.x * 256 + threadIdx.x;
    if (e < E) {
        int d = dst[e];
        atomicAdd(&deg[d], ew[e]);
        atomicAdd(&cnt[d], 1);
    }
}

__global__ void rsqrt_kernel(float* deg, int n) {
    int i = blockIdx.x * 256 + threadIdx.x;
    if (i < n) deg[i] = rsqrtf(deg[i]);
}

// ---------------- parallel exclusive scan (3 kernels) ----------------------
__global__ __launch_bounds__(1024) void scanA_kernel(const int* __restrict__ cnt,
                                                     int* __restrict__ off,
                                                     int* __restrict__ bsum, int n) {
    __shared__ int wsum[16], woff[16];
    int t = threadIdx.x, lane = t & 63, wid = t >> 6;
    int i = blockIdx.x * 1024 + t;
    int v = (i < n) ? cnt[i] : 0;
    int s = v;
    for (int d = 1; d < 64; d <<= 1) { int u = __shfl_up(s, d); if (lane >= d) s += u; }
    if (lane == 63) wsum[wid] = s;
    __syncthreads();
    if (t == 0) {
        int run = 0;
        for (int w = 0; w < 16; w++) { int u = wsum[w]; woff[w] = run; run += u; }
        bsum[blockIdx.x] = run;
    }
    __syncthreads();
    if (i < n) off[i] = woff[wid] + s - v;   // block-local exclusive
}

__global__ void scanB_kernel(int* __restrict__ bsum, int* __restrict__ bscan,
                             int nb, int* __restrict__ off, int n) {
    __shared__ int sh[128];
    int t = threadIdx.x;
    if (t < nb) sh[t] = bsum[t];
    __syncthreads();
    if (t == 0) {
        int run = 0;
        for (int j = 0; j < nb; j++) { int u = sh[j]; sh[j] = run; run += u; }
        off[n] = run;
    }
    __syncthreads();
    if (t < nb) bscan[t] = sh[t];
}

__global__ __launch_bounds__(1024) void scanC_kernel(int* __restrict__ off,
                                                     const int* __restrict__ bscan, int n) {
    int i = blockIdx.x * 1024 + threadIdx.x;
    if (i < n) off[i] += bscan[blockIdx.x];
}

// ---------------- CSR placement + packed meta {src, ew*dinv[src]} ----------
__global__ void csr_kernel(const int* __restrict__ dst, const int* __restrict__ src,
                           const float* __restrict__ ew, const float* __restrict__ dinv,
                           const int* __restrict__ off, int* cur,
                           int2* __restrict__ packed, int E) {
    int e = blockIdx.x * 256 + threadIdx.x;
    if (e < E) {
        int d = dst[e];
        int pos = off[d] + atomicAdd(&cur[d], 1);
        int s = src[e];
        packed[pos] = make_int2(s, __float_as_int(ew[e] * dinv[s]));
    }
}

// ---------------- GEMM: [nrows,128] @ [128,NCOL] -> sliced out -------------
// out layout: [8][nrows][NCOL/8] slice-major. IN_SLICED: x is [8][nrows][16].
template <int NCOL, bool IN_SLICED>
__global__ __launch_bounds__(256) void gemm_kernel(const float* __restrict__ x,
                                                   const float* __restrict__ w,
                                                   float* __restrict__ out, int nrows) {
    constexpr int TX = NCOL / 8;       // 16 or 8
    constexpr int TY = 256 / TX;       // 16 or 32
    constexpr int AR = 64 / TY;        // 4 or 2 rows per thread
    __shared__ float ws[64 * NCOL];
    __shared__ float xs[64 * 68];
    int t = threadIdx.x;
    size_t r0 = (size_t)blockIdx.x * 64;
    int tx = t % TX, ty = t / TX;
    float acc[AR][8];
#pragma unroll
    for (int i = 0; i < AR; i++)
#pragma unroll
        for (int j = 0; j < 8; j++) acc[i][j] = 0.f;

    for (int half = 0; half < 2; half++) {
        __syncthreads();
        for (int f = t; f < 64 * NCOL / 4; f += 256)
            ((float4*)ws)[f] = ((const float4*)(w + half * 64 * NCOL))[f];
        for (int f = t; f < 64 * 16; f += 256) {
            int row = f >> 4, c4 = f & 15;
            int col = half * 64 + c4 * 4;
            float4 v;
            if (IN_SLICED)
                v = *((const float4*)(x + (size_t)(col >> 4) * nrows * 16 +
                                      (r0 + row) * 16 + (col & 15)));
            else
                v = *((const float4*)(x + (r0 + row) * 128 + col));
            *((float4*)(xs + row * 68 + c4 * 4)) = v;
        }
        __syncthreads();
        for (int k = 0; k < 64; k++) {
            float4 b0 = *((const float4*)(ws + k * NCOL + tx * 8));
            float4 b1 = *((const float4*)(ws + k * NCOL + tx * 8 + 4));
            float bb[8] = {b0.x, b0.y, b0.z, b0.w, b1.x, b1.y, b1.z, b1.w};
#pragma unroll
            for (int i = 0; i < AR; i++) {
                float a = xs[(ty * AR + i) * 68 + k];
#pragma unroll
                for (int j = 0; j < 8; j++) acc[i][j] = fmaf(a, bb[j], acc[i][j]);
            }
        }
    }
#pragma unroll
    for (int i = 0; i < AR; i++) {
        size_t row = r0 + ty * AR + i;
        float4 v0 = {acc[i][0], acc[i][1], acc[i][2], acc[i][3]};
        float4 v1 = {acc[i][4], acc[i][5], acc[i][6], acc[i][7]};
        if (NCOL == 128) {
            // slice width 16: slice = tx>>1, within = (tx&1)*8
            size_t base = (size_t)(tx >> 1) * nrows * 16 + row * 16 + (tx & 1) * 8;
            *((float4*)(out + base)) = v0;
            *((float4*)(out + base + 4)) = v1;
        } else {
            // slice width 8: slice = tx
            size_t base = (size_t)tx * nrows * 8 + row * 8;
            *((float4*)(out + base)) = v0;
            *((float4*)(out + base + 4)) = v1;
        }
    }
}

// ---------------- sliced CSR aggregation: out = relu(Ahat z + b) -----------
// slice = blockIdx%8 (XCD-pinned under round-robin). z, out: [8][N1][SW].
template <int C>
__global__ __launch_bounds__(256) void agg_sliced(const float* __restrict__ z,
                                                  const int2* __restrict__ packed,
                                                  const int* __restrict__ off,
                                                  const float* __restrict__ dinv,
                                                  const float* __restrict__ bias,
                                                  float* __restrict__ out, int N1) {
    constexpr int SW = C / 8;        // 16 or 8
    constexpr int NPB = 256 / SW;    // 16 or 32
    int slice = blockIdx.x & 7;
    int g = blockIdx.x >> 3;
    int t = threadIdx.x;
    int sub = t / SW, c = t % SW;
    int d = g * NPB + sub;
    const float* zs = z + (size_t)slice * N1 * SW;
    float dv = dinv[d];
    float acc = dv * zs[(size_t)d * SW + c];
    int e0 = off[d], e1 = off[d + 1];
    for (int e = e0; e < e1; e++) {
        int2 m = packed[e];
        float wn = __int_as_float(m.y);
        acc = fmaf(wn, zs[(size_t)m.x * SW + c], acc);
    }
    out[(size_t)slice * N1 * SW + (size_t)d * SW + c] =
        fmaxf(dv * acc + bias[slice * SW + c], 0.f);
}

// ---------------- graph2 (row-major, tiny) ---------------------------------
__global__ void g2_prep(const int* __restrict__ ei2, const float* __restrict__ ew2,
                        float* dinv2, float* a2a, float* a2b, int E2, int N2) {
    __shared__ float degl[256];
    int t = threadIdx.x;
    degl[t] = 1.0f;
    __syncthreads();
    for (int e = t; e < E2; e += 256) atomicAdd(&degl[ei2[E2 + e]], ew2[e]);
    __syncthreads();
    if (t < N2) dinv2[t] = rsqrtf(degl[t]);
    for (int i = t; i < N2 * 128; i += 256) a2a[i] = 0.f;
    for (int i = t; i < N2 * 64; i += 256) a2b[i] = 0.f;
}

template <int NCOL>
__global__ void g2_gemm(const float* __restrict__ x, const float* __restrict__ w,
                        float* __restrict__ z, int N2) {
    __shared__ float xr[128];
    int row = blockIdx.x, t = threadIdx.x;
    for (int k = t; k < 128; k += NCOL) xr[k] = x[row * 128 + k];
    __syncthreads();
    float acc = 0.f;
    for (int k = 0; k < 128; k++) acc = fmaf(xr[k], w[k * NCOL + t], acc);
    z[row * NCOL + t] = acc;
}

template <int C>
__global__ void g2_scatter(const float* __restrict__ z, const int* __restrict__ ei2,
                           const float* __restrict__ ew2, const float* __restrict__ dinv2,
                           float* a2, int E2) {
    constexpr int CPL = C / 64;
    int wid = threadIdx.x >> 6, lane = threadIdx.x & 63;
    int e = blockIdx.x * 4 + wid;
    if (e >= E2) return;
    int s = ei2[e], d = ei2[E2 + e];
    float nm = dinv2[s] * ew2[e] * dinv2[d];
#pragma unroll
    for (int q = 0; q < CPL; q++) {
        int c = lane * CPL + q;
        atomicAdd(&a2[d * C + c], nm * z[s * C + c]);
    }
}

template <int C>
__global__ void g2_fin(const float* __restrict__ a2, const float* __restrict__ z,
                       const float* __restrict__ dinv2, const float* __restrict__ bias,
                       float* __restrict__ out, int N2) {
    int i = blockIdx.x * 256 + threadIdx.x;
    if (i >= N2 * C) return;
    int n = i / C, c = i % C;
    float dv = dinv2[n];
    out[i] = fmaxf(a2[i] + dv * dv * z[i] + bias[c], 0.f);
}

__global__ void s2_kernel(const float* __restrict__ o2, float* s2, int N2) {
    int wid = threadIdx.x >> 6, lane = threadIdx.x & 63;
    int j = blockIdx.x * 4 + wid;
    if (j >= N2) return;
    float v = o2[j * 64 + lane];
    float ss = v * v;
    for (int d = 32; d >= 1; d >>= 1) ss += __shfl_xor(ss, d);
    if (lane == 0) s2[j] = ss;
}

// ---------------- dlast: o1 is sliced [8][N1][8] ---------------------------
__global__ void dlast_kernel(const float* __restrict__ o1, const float* __restrict__ o2,
                             const float* __restrict__ s2, float* __restrict__ dlast,
                             int n, int N2) {
    int wid = threadIdx.x >> 6, lane = threadIdx.x & 63;
    int i = blockIdx.x * 4 + wid;
    if (i >= n) return;
    float a = o1[(size_t)(lane >> 3) * n * 8 + (size_t)i * 8 + (lane & 7)];
    float b = o2[(size_t)(N2 - 1) * 64 + lane];
    float aa = a * a, ab = a * b;
    for (int d = 32; d >= 1; d >>= 1) { aa += __shfl_xor(aa, d); ab += __shfl_xor(ab, d); }
    if (lane == 0) {
        float d2 = aa + s2[N2 - 1] - 2.f * ab;
        dlast[i] = sqrtf(fmaxf(d2, 0.f) + 1e-12f);
    }
}

// ---------------- top-K per graph (wave-shfl argmax, stable ties) ----------
__global__ __launch_bounds__(256) void topk_kernel(const float* __restrict__ dlast,
                                                   int* __restrict__ topidx,
                                                   int NPG, int K) {
    __shared__ unsigned long long keys[1600];
    __shared__ unsigned long long wmax[4];
    int g = blockIdx.x, t = threadIdx.x;
    int lane = t & 63, wid = t >> 6;
    for (int r = t; r < NPG; r += 256) {
        unsigned vb = __float_as_uint(dlast[(size_t)g * NPG + r]);  // dist > 0
        keys[r] = ((unsigned long long)vb << 32) | (unsigned)(NPG - 1 - r);
    }
    __syncthreads();
    for (int it = 0; it < K; it++) {
        unsigned long long m = 0ull;
        for (int r = t; r < NPG; r += 256) { unsigned long long k = keys[r]; if (k > m) m = k; }
        for (int d = 32; d >= 1; d >>= 1) {
            unsigned long long u = __shfl_xor(m, d);
            if (u > m) m = u;
        }
        if (lane == 0) wmax[wid] = m;
        __syncthreads();
        if (t == 0) {
            unsigned long long mm = wmax[0];
            for (int w = 1; w < 4; w++) if (wmax[w] > mm) mm = wmax[w];
            int rbest = NPG - 1 - (int)(mm & 0xffffffffull);
            topidx[g * K + it] = rbest;
            keys[rbest] = 0ull;
        }
        __syncthreads();
    }
}

// ---------------- pooled rows: o1 sliced -----------------------------------
__global__ void pooled_kernel(const float* __restrict__ o1, const float* __restrict__ o2,
                              const float* __restrict__ s2, const int* __restrict__ topidx,
                              float* __restrict__ pooled, int NPG, int K, int N2, int N1) {
    __shared__ float o1s[64];
    __shared__ float s1sh;
    int g = blockIdx.x / K, kk = blockIdx.x % K;
    int t = threadIdx.x;
    int r = topidx[g * K + kk];
    size_t node = (size_t)g * NPG + r;
    if (t < 64) o1s[t] = o1[(size_t)(t >> 3) * N1 * 8 + node * 8 + (t & 7)];
    __syncthreads();
    if (t < 64) {
        float v = o1s[t]; float ss = v * v;
        for (int d = 32; d >= 1; d >>= 1) ss += __shfl_xor(ss, d);
        if (t == 0) s1sh = ss;
    }
    __syncthreads();
    if (t < N2) {
        float dot = 0.f;
#pragma unroll 8
        for (int k2 = 0; k2 < 64; k2++) dot = fmaf(o1s[k2], o2[t * 64 + k2], dot);
        float d2 = s1sh + s2[t] - 2.f * dot;
        pooled[(size_t)blockIdx.x * N2 + t] = sqrtf(fmaxf(d2, 0.f) + 1e-12f);
    }
}

// ---------------- fc1 split-K partial GEMM ---------------------------------
#define FC1_CH 256
__global__ __launch_bounds__(256) void fc1_kernel(const float* __restrict__ pooled,
                                                  const float* __restrict__ fc1W,
                                                  float* __restrict__ h1p,
                                                  int PK, int NCHUNK, int B) {
    __shared__ float ps[FC1_CH];
    __shared__ float red[256];
    int b = blockIdx.x % B, ch = blockIdx.x / B;
    int r0 = ch * FC1_CH;
    int nr = min(FC1_CH, PK - r0);
    int t = threadIdx.x;
    for (int i = t; i < nr; i += 256) ps[i] = pooled[(size_t)b * PK + r0 + i];
    __syncthreads();
    int c = t & 127, half = t >> 7;
    int rb = half * (FC1_CH / 2);
    int re = min(rb + FC1_CH / 2, nr);
    float acc = 0.f;
    for (int r = rb; r < re; r++)
        acc = fmaf(ps[r], fc1W[(size_t)(r0 + r) * 128 + c], acc);
    red[t] = acc;
    __syncthreads();
    if (t < 128) h1p[((size_t)b * NCHUNK + ch) * 128 + t] = red[t] + red[t + 128];
}

// ---------------- head tail --------------------------------------------------
__global__ __launch_bounds__(256) void head2_kernel(
    const float* __restrict__ h1p, int NCHUNK,
    const float* __restrict__ fc1b, const float* __restrict__ ln1g,
    const float* __restrict__ ln1b, const float* __restrict__ fc2W,
    const float* __restrict__ fc2b, const float* __restrict__ ln2g,
    const float* __restrict__ ln2b, const float* __restrict__ fc3W,
    const float* __restrict__ fc3b, float* __restrict__ out) {
    __shared__ float red[256];
    __shared__ float h1[128];
    __shared__ float h2[64];
    int b = blockIdx.x, t = threadIdx.x;
    if (t < 128) {
        float s = 0.f;
        for (int ch = 0; ch < NCHUNK; ch++)
            s += h1p[((size_t)b * NCHUNK + ch) * 128 + t];
        h1[t] = s + fc1b[t];
    }
    __syncthreads();
    red[t] = (t < 128) ? h1[t] : 0.f;
    __syncthreads();
    for (int s = 128; s >= 1; s >>= 1) { if (t < s) red[t] += red[t + s]; __syncthreads(); }
    float mean1 = red[0] / 128.f;
    __syncthreads();
    float dv1 = (t < 128) ? (h1[t] - mean1) : 0.f;
    red[t] = dv1 * dv1;
    __syncthreads();
    for (int s = 128; s >= 1; s >>= 1) { if (t < s) red[t] += red[t + s]; __syncthreads(); }
    float var1 = red[0] / 128.f;
    __syncthreads();
    if (t < 128) {
        float y = (h1[t] - mean1) * rsqrtf(var1 + 1e-5f) * ln1g[t] + ln1b[t];
        h1[t] = fmaxf(y, 0.f);
    }
    __syncthreads();
    if (t < 64) {
        float a2v = 0.f;
        for (int k2 = 0; k2 < 128; k2++) a2v = fmaf(h1[k2], fc2W[k2 * 64 + t], a2v);
        h2[t] = a2v + fc2b[t];
    }
    __syncthreads();
    red[t] = (t < 64) ? h2[t] : 0.f;
    __syncthreads();
    for (int s = 128; s >= 1; s >>= 1) { if (t < s) red[t] += red[t + s]; __syncthreads(); }
    float mean2 = red[0] / 64.f;
    __syncthreads();
    float dv2 = (t < 64) ? (h2[t] - mean2) : 0.f;
    red[t] = dv2 * dv2;
    __syncthreads();
    for (int s = 128; s >= 1; s >>= 1) { if (t < s) red[t] += red[t + s]; __syncthreads(); }
    float var2 = red[0] / 64.f;
    __syncthreads();
    if (t < 64)
        h2[t] = fmaxf((h2[t] - mean2) * rsqrtf(var2 + 1e-5f) * ln2g[t] + ln2b[t], 0.f);
    __syncthreads();
    red[t] = (t < 64) ? h2[t] * fc3W[t] : 0.f;
    __syncthreads();
    for (int s = 128; s >= 1; s >>= 1) { if (t < s) red[t] += red[t + s]; __syncthreads(); }
    if (t == 0) out[b] = 1.f / (1.f + expf(-(red[0] + fc3b[0])));
}

// ---------------------------------------------------------------------------
extern "C" void kernel_launch(void* const* d_in, const int* in_sizes, int n_in,
                              void* d_out, int out_size, void* d_ws, size_t ws_size,
                              hipStream_t stream) {
    const float* x1   = (const float*)d_in[0];
    const float* ew1  = (const float*)d_in[1];
    const float* x2   = (const float*)d_in[2];
    const float* ew2  = (const float*)d_in[3];
    const float* Wg1  = (const float*)d_in[4];
    const float* bg1  = (const float*)d_in[5];
    const float* Wg2  = (const float*)d_in[6];
    const float* bg2  = (const float*)d_in[7];
    const float* fc1W = (const float*)d_in[8];
    const float* fc1b = (const float*)d_in[9];
    const float* ln1g = (const float*)d_in[10];
    const float* ln1b = (const float*)d_in[11];
    const float* fc2W = (const float*)d_in[12];
    const float* fc2b = (const float*)d_in[13];
    const float* ln2g = (const float*)d_in[14];
    const float* ln2b = (const float*)d_in[15];
    const float* fc3W = (const float*)d_in[16];
    const float* fc3b = (const float*)d_in[17];
    const int* ei1    = (const int*)d_in[18];
    const int* ei2    = (const int*)d_in[19];
    float* out = (float*)d_out;

    const int N1 = in_sizes[0] / 128;        // 102400
    const int E1 = in_sizes[1];              // 1638400
    const int N2 = in_sizes[2] / 128;        // 199
    const int E2 = in_sizes[3];              // 3184
    const int B  = out_size;                 // 64
    const int NPG = N1 / B;                  // 1600
    const int K  = (in_sizes[8] / 128) / N2; // 50
    const int PK = K * N2;                   // 9950
    const int NCHUNK = (PK + FC1_CH - 1) / FC1_CH;  // 39
    const int NB1024 = (N1 + 1023) / 1024;   // 100

    char* wsb = (char*)d_ws;
    size_t o = 0;
    auto alloc = [&](size_t bytes) -> void* {
        void* p = wsb + o;
        o += (bytes + 255) & ~(size_t)255;
        return p;
    };
    float* deg1   = (float*)alloc((size_t)N1 * 4);        // becomes dinv1
    int*   cnt    = (int*)alloc((size_t)N1 * 4);
    int*   cur    = (int*)alloc((size_t)N1 * 4);
    int*   off    = (int*)alloc((size_t)(N1 + 1) * 4);
    int*   bsum   = (int*)alloc(128 * 4);
    int*   bscan  = (int*)alloc(128 * 4);
    int2*  packed = (int2*)alloc((size_t)E1 * 8);
    float* z      = (float*)alloc((size_t)N1 * 128 * 4);  // sliced z1, then z2
    float* h      = (float*)alloc((size_t)N1 * 128 * 4);  // sliced h1, then o1
    float* dl     = (float*)alloc((size_t)N1 * 4);
    int*   tki    = (int*)alloc((size_t)B * K * 4);
    float* pooled = (float*)alloc((size_t)B * K * N2 * 4);
    float* h1p    = (float*)alloc((size_t)B * NCHUNK * 128 * 4);
    float* dinv2  = (float*)alloc((size_t)N2 * 4);
    float* z2g    = (float*)alloc((size_t)N2 * 128 * 4);
    float* h2b    = (float*)alloc((size_t)N2 * 128 * 4);
    float* a2a    = (float*)alloc((size_t)N2 * 128 * 4);
    float* zz2    = (float*)alloc((size_t)N2 * 64 * 4);
    float* a2b    = (float*)alloc((size_t)N2 * 64 * 4);
    float* o2b    = (float*)alloc((size_t)N2 * 64 * 4);
    float* s2     = (float*)alloc((size_t)N2 * 4);
    (void)ws_size; (void)n_in;

    const int* src1 = ei1;
    const int* dst1 = ei1 + E1;

    // -------- graph1 CSR build --------
    init1_kernel<<<(N1 + 255) / 256, 256, 0, stream>>>(deg1, cnt, cur, N1);
    hist_kernel<<<(E1 + 255) / 256, 256, 0, stream>>>(dst1, ew1, deg1, cnt, E1);
    rsqrt_kernel<<<(N1 + 255) / 256, 256, 0, stream>>>(deg1, N1);
    scanA_kernel<<<NB1024, 1024, 0, stream>>>(cnt, off, bsum, N1);
    scanB_kernel<<<1, 256, 0, stream>>>(bsum, bscan, NB1024, off, N1);
    scanC_kernel<<<NB1024, 1024, 0, stream>>>(off, bscan, N1);
    csr_kernel<<<(E1 + 255) / 256, 256, 0, stream>>>(dst1, src1, ew1, deg1, off, cur, packed, E1);

    // -------- graph1 GNN (sliced layouts) --------
    gemm_kernel<128, false><<<N1 / 64, 256, 0, stream>>>(x1, Wg1, z, N1);
    agg_sliced<128><<<(N1 / 16) * 8, 256, 0, stream>>>(z, packed, off, deg1, bg1, h, N1);
    gemm_kernel<64, true><<<N1 / 64, 256, 0, stream>>>(h, Wg2, z, N1);   // z := z2 sliced
    agg_sliced<64><<<(N1 / 32) * 8, 256, 0, stream>>>(z, packed, off, deg1, bg2, h, N1); // h := o1

    // -------- graph2 GNN (row-major, tiny) --------
    g2_prep<<<1, 256, 0, stream>>>(ei2, ew2, dinv2, a2a, a2b, E2, N2);
    g2_gemm<128><<<N2, 128, 0, stream>>>(x2, Wg1, z2g, N2);
    g2_scatter<128><<<(E2 + 3) / 4, 256, 0, stream>>>(z2g, ei2, ew2, dinv2, a2a, E2);
    g2_fin<128><<<(N2 * 128 + 255) / 256, 256, 0, stream>>>(a2a, z2g, dinv2, bg1, h2b, N2);
    g2_gemm<64><<<N2, 64, 0, stream>>>(h2b, Wg2, zz2, N2);
    g2_scatter<64><<<(E2 + 3) / 4, 256, 0, stream>>>(zz2, ei2, ew2, dinv2, a2b, E2);
    g2_fin<64><<<(N2 * 64 + 255) / 256, 256, 0, stream>>>(a2b, zz2, dinv2, bg2, o2b, N2);

    // -------- cdist (partial) + SortAggregation + head --------
    s2_kernel<<<(N2 + 3) / 4, 256, 0, stream>>>(o2b, s2, N2);
    dlast_kernel<<<(N1 + 3) / 4, 256, 0, stream>>>(h, o2b, s2, dl, N1, N2);
    topk_kernel<<<B, 256, 0, stream>>>(dl, tki, NPG, K);
    pooled_kernel<<<B * K, 256, 0, stream>>>(h, o2b, s2, tki, pooled, NPG, K, N2, N1);
    fc1_kernel<<<NCHUNK * B, 256, 0, stream>>>(pooled, fc1W, h1p, PK, NCHUNK, B);
    head2_kernel<<<B, 256, 0, stream>>>(h1p, NCHUNK, fc1b, ln1g, ln1b, fc2W, fc2b,
                                        ln2g, ln2b, fc3W, fc3b, out);
}

// Round 4
// 692.035 us; speedup vs baseline: 1.5428x; 1.5428x over previous
//
#include <hip/hip_runtime.h>
#include <hip/hip_bf16.h>
#include <cstdint>

// ---------------------------------------------------------------------------
// SiameseGNN. R4: row-major full-row gathers (512B/edge) with scalar-uniform
// CSR edge loop (readfirstlane -> s_load meta) and 4x unroll for 4 gathers in
// flight per wave. Packed edge meta {src, ew*dinv[src]}. Parallel scan.
// dlast fused into agg64 epilogue; s2 fused into g2_fin64.
// ---------------------------------------------------------------------------

__device__ __forceinline__ int rfl(int v) { return __builtin_amdgcn_readfirstlane(v); }

// ---------------- init: deg1=1.0 (self loop), cnt=0, cur=0 -----------------
__global__ void init1_kernel(float* deg, int* cnt, int* cur, int n) {
    int i = blockIdx.x * 256 + threadIdx.x;
    if (i < n) { deg[i] = 1.0f; cnt[i] = 0; cur[i] = 0; }
}

__global__ void hist_kernel(const int* __restrict__ dst, const float* __restrict__ ew,
                            float* deg, int* cnt, int E) {
    int e = blockIdx.x * 256 + threadIdx.x;
    if (e < E) {
        int d = dst[e];
        atomicAdd(&deg[d], ew[e]);
        atomicAdd(&cnt[d], 1);
    }
}

__global__ void rsqrt_kernel(float* deg, int n) {
    int i = blockIdx.x * 256 + threadIdx.x;
    if (i < n) deg[i] = rsqrtf(deg[i]);
}

// ---------------- parallel exclusive scan (3 kernels) ----------------------
__global__ __launch_bounds__(1024) void scanA_kernel(const int* __restrict__ cnt,
                                                     int* __restrict__ off,
                                                     int* __restrict__ bsum, int n) {
    __shared__ int wsum[16], woff[16];
    int t = threadIdx.x, lane = t & 63, wid = t >> 6;
    int i = blockIdx.x * 1024 + t;
    int v = (i < n) ? cnt[i] : 0;
    int s = v;
    for (int d = 1; d < 64; d <<= 1) { int u = __shfl_up(s, d); if (lane >= d) s += u; }
    if (lane == 63) wsum[wid] = s;
    __syncthreads();
    if (t == 0) {
        int run = 0;
        for (int w = 0; w < 16; w++) { int u = wsum[w]; woff[w] = run; run += u; }
        bsum[blockIdx.x] = run;
    }
    __syncthreads();
    if (i < n) off[i] = woff[wid] + s - v;   // block-local exclusive
}

__global__ void scanB_kernel(int* __restrict__ bsum, int* __restrict__ bscan,
                             int nb, int* __restrict__ off, int n) {
    __shared__ int sh[128];
    int t = threadIdx.x;
    if (t < nb) sh[t] = bsum[t];
    __syncthreads();
    if (t == 0) {
        int run = 0;
        for (int j = 0; j < nb; j++) { int u = sh[j]; sh[j] = run; run += u; }
        off[n] = run;
    }
    __syncthreads();
    if (t < nb) bscan[t] = sh[t];
}

__global__ __launch_bounds__(1024) void scanC_kernel(int* __restrict__ off,
                                                     const int* __restrict__ bscan, int n) {
    int i = blockIdx.x * 1024 + threadIdx.x;
    if (i < n) off[i] += bscan[blockIdx.x];
}

// ---------------- CSR placement + packed meta {src, ew*dinv[src]} ----------
__global__ void csr_kernel(const int* __restrict__ dst, const int* __restrict__ src,
                           const float* __restrict__ ew, const float* __restrict__ dinv,
                           const int* __restrict__ off, int* cur,
                           int2* __restrict__ packed, int E) {
    int e = blockIdx.x * 256 + threadIdx.x;
    if (e < E) {
        int d = dst[e];
        int pos = off[d] + atomicAdd(&cur[d], 1);
        int s = src[e];
        packed[pos] = make_int2(s, __float_as_int(ew[e] * dinv[s]));
    }
}

// ---------------- GEMM: [nrows,128] @ [128,NCOL] -> [nrows,NCOL] -----------
template <int NCOL>
__global__ __launch_bounds__(256) void gemm_kernel(const float* __restrict__ x,
                                                   const float* __restrict__ w,
                                                   float* __restrict__ out, int nrows) {
    constexpr int TX = NCOL / 8;       // 16 or 8
    constexpr int TY = 256 / TX;       // 16 or 32
    constexpr int AR = 64 / TY;        // 4 or 2 rows per thread
    __shared__ float ws[64 * NCOL];
    __shared__ float xs[64 * 68];
    int t = threadIdx.x;
    size_t r0 = (size_t)blockIdx.x * 64;
    int tx = t % TX, ty = t / TX;
    float acc[AR][8];
#pragma unroll
    for (int i = 0; i < AR; i++)
#pragma unroll
        for (int j = 0; j < 8; j++) acc[i][j] = 0.f;

    for (int half = 0; half < 2; half++) {
        __syncthreads();
        for (int f = t; f < 64 * NCOL / 4; f += 256)
            ((float4*)ws)[f] = ((const float4*)(w + half * 64 * NCOL))[f];
        for (int f = t; f < 64 * 16; f += 256) {
            int row = f >> 4, c4 = f & 15;
            float4 v = *((const float4*)(x + (r0 + row) * 128 + half * 64 + c4 * 4));
            *((float4*)(xs + row * 68 + c4 * 4)) = v;
        }
        __syncthreads();
        for (int k = 0; k < 64; k++) {
            float4 b0 = *((const float4*)(ws + k * NCOL + tx * 8));
            float4 b1 = *((const float4*)(ws + k * NCOL + tx * 8 + 4));
            float bb[8] = {b0.x, b0.y, b0.z, b0.w, b1.x, b1.y, b1.z, b1.w};
#pragma unroll
            for (int i = 0; i < AR; i++) {
                float a = xs[(ty * AR + i) * 68 + k];
#pragma unroll
                for (int j = 0; j < 8; j++) acc[i][j] = fmaf(a, bb[j], acc[i][j]);
            }
        }
    }
#pragma unroll
    for (int i = 0; i < AR; i++) {
        size_t row = r0 + ty * AR + i;
        float4 v0 = {acc[i][0], acc[i][1], acc[i][2], acc[i][3]};
        float4 v1 = {acc[i][4], acc[i][5], acc[i][6], acc[i][7]};
        *((float4*)(out + row * NCOL + tx * 8)) = v0;
        *((float4*)(out + row * NCOL + tx * 8 + 4)) = v1;
    }
}

// ---------------- CSR aggregation, scalar-uniform edge loop ----------------
// One wave per node. d forced wave-uniform -> off/packed reads become scalar
// loads; 4x unrolled so 4 full-row gathers (512B/256B) are in flight.
// FUSE_DLAST (C=64): also emit dlast[d] = dist(o1_row, o2[N2-1]).
template <int C, bool FUSE_DLAST>
__global__ __launch_bounds__(256) void agg_kernel(const float* __restrict__ z,
                                                  const int2* __restrict__ packed,
                                                  const int* __restrict__ off,
                                                  const float* __restrict__ dinv,
                                                  const float* __restrict__ bias,
                                                  float* __restrict__ out, int n,
                                                  const float* __restrict__ o2,
                                                  const float* __restrict__ s2,
                                                  float* __restrict__ dlast, int N2) {
    int wid = threadIdx.x >> 6;
    int lane = threadIdx.x & 63;
    int d = rfl(blockIdx.x * 4 + wid);
    if (d >= n) return;
    float dv = dinv[d];
    float acc0, acc1 = 0.f;
    float b0, b1 = 0.f;
    if (C == 128) {
        float2 zv = *((const float2*)(z + (size_t)d * C + lane * 2));
        acc0 = dv * zv.x; acc1 = dv * zv.y;
        float2 bv = *((const float2*)(bias + lane * 2));
        b0 = bv.x; b1 = bv.y;
    } else {
        acc0 = dv * z[(size_t)d * C + lane];
        b0 = bias[lane];
    }
    int e0 = off[d], e1 = off[d + 1];
    int e = e0;
    for (; e + 4 <= e1; e += 4) {
        int2 m0 = packed[e], m1 = packed[e + 1], m2 = packed[e + 2], m3 = packed[e + 3];
        int s0 = rfl(m0.x), s1 = rfl(m1.x), s2i = rfl(m2.x), s3 = rfl(m3.x);
        float w0 = __int_as_float(rfl(m0.y)), w1 = __int_as_float(rfl(m1.y));
        float w2 = __int_as_float(rfl(m2.y)), w3 = __int_as_float(rfl(m3.y));
        if (C == 128) {
            float2 v0 = *((const float2*)(z + (size_t)s0 * C + lane * 2));
            float2 v1 = *((const float2*)(z + (size_t)s1 * C + lane * 2));
            float2 v2 = *((const float2*)(z + (size_t)s2i * C + lane * 2));
            float2 v3 = *((const float2*)(z + (size_t)s3 * C + lane * 2));
            acc0 = fmaf(w0, v0.x, acc0); acc1 = fmaf(w0, v0.y, acc1);
            acc0 = fmaf(w1, v1.x, acc0); acc1 = fmaf(w1, v1.y, acc1);
            acc0 = fmaf(w2, v2.x, acc0); acc1 = fmaf(w2, v2.y, acc1);
            acc0 = fmaf(w3, v3.x, acc0); acc1 = fmaf(w3, v3.y, acc1);
        } else {
            float v0 = z[(size_t)s0 * C + lane];
            float v1 = z[(size_t)s1 * C + lane];
            float v2 = z[(size_t)s2i * C + lane];
            float v3 = z[(size_t)s3 * C + lane];
            acc0 = fmaf(w0, v0, acc0);
            acc0 = fmaf(w1, v1, acc0);
            acc0 = fmaf(w2, v2, acc0);
            acc0 = fmaf(w3, v3, acc0);
        }
    }
    for (; e < e1; e++) {
        int2 m = packed[e];
        int s = rfl(m.x);
        float w = __int_as_float(rfl(m.y));
        if (C == 128) {
            float2 v = *((const float2*)(z + (size_t)s * C + lane * 2));
            acc0 = fmaf(w, v.x, acc0); acc1 = fmaf(w, v.y, acc1);
        } else {
            acc0 = fmaf(w, z[(size_t)s * C + lane], acc0);
        }
    }
    if (C == 128) {
        int c = lane * 2;
        float2 ov = {fmaxf(dv * acc0 + b0, 0.f), fmaxf(dv * acc1 + b1, 0.f)};
        *((float2*)(out + (size_t)d * C + c)) = ov;
    } else {
        float a = fmaxf(dv * acc0 + b0, 0.f);
        out[(size_t)d * C + lane] = a;
        if (FUSE_DLAST) {
            float bl = o2[(size_t)(N2 - 1) * 64 + lane];
            float aa = a * a, ab = a * bl;
            for (int dd = 32; dd >= 1; dd >>= 1) {
                aa += __shfl_xor(aa, dd);
                ab += __shfl_xor(ab, dd);
            }
            if (lane == 0) {
                float d2 = aa + s2[N2 - 1] - 2.f * ab;
                dlast[d] = sqrtf(fmaxf(d2, 0.f) + 1e-12f);
            }
        }
    }
}

// ---------------- graph2 (row-major, tiny) ---------------------------------
__global__ void g2_prep(const int* __restrict__ ei2, const float* __restrict__ ew2,
                        float* dinv2, float* a2a, float* a2b, int E2, int N2) {
    __shared__ float degl[256];
    int t = threadIdx.x;
    degl[t] = 1.0f;
    __syncthreads();
    for (int e = t; e < E2; e += 256) atomicAdd(&degl[ei2[E2 + e]], ew2[e]);
    __syncthreads();
    if (t < N2) dinv2[t] = rsqrtf(degl[t]);
    for (int i = t; i < N2 * 128; i += 256) a2a[i] = 0.f;
    for (int i = t; i < N2 * 64; i += 256) a2b[i] = 0.f;
}

template <int NCOL>
__global__ void g2_gemm(const float* __restrict__ x, const float* __restrict__ w,
                        float* __restrict__ z, int N2) {
    __shared__ float xr[128];
    int row = blockIdx.x, t = threadIdx.x;
    for (int k = t; k < 128; k += NCOL) xr[k] = x[row * 128 + k];
    __syncthreads();
    float acc = 0.f;
    for (int k = 0; k < 128; k++) acc = fmaf(xr[k], w[k * NCOL + t], acc);
    z[row * NCOL + t] = acc;
}

template <int C>
__global__ void g2_scatter(const float* __restrict__ z, const int* __restrict__ ei2,
                           const float* __restrict__ ew2, const float* __restrict__ dinv2,
                           float* a2, int E2) {
    constexpr int CPL = C / 64;
    int wid = threadIdx.x >> 6, lane = threadIdx.x & 63;
    int e = blockIdx.x * 4 + wid;
    if (e >= E2) return;
    int s = ei2[e], d = ei2[E2 + e];
    float nm = dinv2[s] * ew2[e] * dinv2[d];
#pragma unroll
    for (int q = 0; q < CPL; q++) {
        int c = lane * CPL + q;
        atomicAdd(&a2[d * C + c], nm * z[s * C + c]);
    }
}

__global__ void g2_fin128(const float* __restrict__ a2, const float* __restrict__ z,
                          const float* __restrict__ dinv2, const float* __restrict__ bias,
                          float* __restrict__ out, int N2) {
    int i = blockIdx.x * 256 + threadIdx.x;
    if (i >= N2 * 128) return;
    int n = i / 128, c = i % 128;
    float dv = dinv2[n];
    out[i] = fmaxf(a2[i] + dv * dv * z[i] + bias[c], 0.f);
}

// fin for C=64 with fused row-norm s2
__global__ void g2_fin64s2(const float* __restrict__ a2, const float* __restrict__ z,
                           const float* __restrict__ dinv2, const float* __restrict__ bias,
                           float* __restrict__ out, float* __restrict__ s2, int N2) {
    int wid = threadIdx.x >> 6, lane = threadIdx.x & 63;
    int row = blockIdx.x * 4 + wid;
    if (row >= N2) return;
    int i = row * 64 + lane;
    float dv = dinv2[row];
    float v = fmaxf(a2[i] + dv * dv * z[i] + bias[lane], 0.f);
    out[i] = v;
    float ss = v * v;
    for (int d = 32; d >= 1; d >>= 1) ss += __shfl_xor(ss, d);
    if (lane == 0) s2[row] = ss;
}

// ---------------- top-K per graph (wave-shfl argmax, stable ties) ----------
__global__ __launch_bounds__(256) void topk_kernel(const float* __restrict__ dlast,
                                                   int* __restrict__ topidx,
                                                   int NPG, int K) {
    __shared__ unsigned long long keys[1600];
    __shared__ unsigned long long wmax[4];
    int g = blockIdx.x, t = threadIdx.x;
    int lane = t & 63, wid = t >> 6;
    for (int r = t; r < NPG; r += 256) {
        unsigned vb = __float_as_uint(dlast[(size_t)g * NPG + r]);  // dist > 0
        keys[r] = ((unsigned long long)vb << 32) | (unsigned)(NPG - 1 - r);
    }
    __syncthreads();
    for (int it = 0; it < K; it++) {
        unsigned long long m = 0ull;
        for (int r = t; r < NPG; r += 256) { unsigned long long k = keys[r]; if (k > m) m = k; }
        for (int d = 32; d >= 1; d >>= 1) {
            unsigned long long u = __shfl_xor(m, d);
            if (u > m) m = u;
        }
        if (lane == 0) wmax[wid] = m;
        __syncthreads();
        if (t == 0) {
            unsigned long long mm = wmax[0];
            for (int w = 1; w < 4; w++) if (wmax[w] > mm) mm = wmax[w];
            int rbest = NPG - 1 - (int)(mm & 0xffffffffull);
            topidx[g * K + it] = rbest;
            keys[rbest] = 0ull;
        }
        __syncthreads();
    }
}

// ---------------- pooled rows: dist(o1[sel], o2[j]) for j<N2 ---------------
__global__ void pooled_kernel(const float* __restrict__ o1, const float* __restrict__ o2,
                              const float* __restrict__ s2, const int* __restrict__ topidx,
                              float* __restrict__ pooled, int NPG, int K, int N2) {
    __shared__ float o1s[64];
    __shared__ float s1sh;
    int g = blockIdx.x / K, kk = blockIdx.x % K;
    int t = threadIdx.x;
    int r = topidx[g * K + kk];
    size_t node = (size_t)g * NPG + r;
    if (t < 64) o1s[t] = o1[node * 64 + t];
    __syncthreads();
    if (t < 64) {
        float v = o1s[t]; float ss = v * v;
        for (int d = 32; d >= 1; d >>= 1) ss += __shfl_xor(ss, d);
        if (t == 0) s1sh = ss;
    }
    __syncthreads();
    if (t < N2) {
        float dot = 0.f;
#pragma unroll 8
        for (int k2 = 0; k2 < 64; k2++) dot = fmaf(o1s[k2], o2[t * 64 + k2], dot);
        float d2 = s1sh + s2[t] - 2.f * dot;
        pooled[(size_t)blockIdx.x * N2 + t] = sqrtf(fmaxf(d2, 0.f) + 1e-12f);
    }
}

// ---------------- fc1 split-K partial GEMM ---------------------------------
#define FC1_CH 256
__global__ __launch_bounds__(256) void fc1_kernel(const float* __restrict__ pooled,
                                                  const float* __restrict__ fc1W,
                                                  float* __restrict__ h1p,
                                                  int PK, int NCHUNK, int B) {
    __shared__ float ps[FC1_CH];
    __shared__ float red[256];
    int b = blockIdx.x % B, ch = blockIdx.x / B;
    int r0 = ch * FC1_CH;
    int nr = min(FC1_CH, PK - r0);
    int t = threadIdx.x;
    for (int i = t; i < nr; i += 256) ps[i] = pooled[(size_t)b * PK + r0 + i];
    __syncthreads();
    int c = t & 127, half = t >> 7;
    int rb = half * (FC1_CH / 2);
    int re = min(rb + FC1_CH / 2, nr);
    float acc = 0.f;
    for (int r = rb; r < re; r++)
        acc = fmaf(ps[r], fc1W[(size_t)(r0 + r) * 128 + c], acc);
    red[t] = acc;
    __syncthreads();
    if (t < 128) h1p[((size_t)b * NCHUNK + ch) * 128 + t] = red[t] + red[t + 128];
}

// ---------------- head tail ------------------------------------------------
__global__ __launch_bounds__(256) void head2_kernel(
    const float* __restrict__ h1p, int NCHUNK,
    const float* __restrict__ fc1b, const float* __restrict__ ln1g,
    const float* __restrict__ ln1b, const float* __restrict__ fc2W,
    const float* __restrict__ fc2b, const float* __restrict__ ln2g,
    const float* __restrict__ ln2b, const float* __restrict__ fc3W,
    const float* __restrict__ fc3b, float* __restrict__ out) {
    __shared__ float red[256];
    __shared__ float h1[128];
    __shared__ float h2[64];
    int b = blockIdx.x, t = threadIdx.x;
    if (t < 128) {
        float s = 0.f;
        for (int ch = 0; ch < NCHUNK; ch++)
            s += h1p[((size_t)b * NCHUNK + ch) * 128 + t];
        h1[t] = s + fc1b[t];
    }
    __syncthreads();
    red[t] = (t < 128) ? h1[t] : 0.f;
    __syncthreads();
    for (int s = 128; s >= 1; s >>= 1) { if (t < s) red[t] += red[t + s]; __syncthreads(); }
    float mean1 = red[0] / 128.f;
    __syncthreads();
    float dv1 = (t < 128) ? (h1[t] - mean1) : 0.f;
    red[t] = dv1 * dv1;
    __syncthreads();
    for (int s = 128; s >= 1; s >>= 1) { if (t < s) red[t] += red[t + s]; __syncthreads(); }
    float var1 = red[0] / 128.f;
    __syncthreads();
    if (t < 128) {
        float y = (h1[t] - mean1) * rsqrtf(var1 + 1e-5f) * ln1g[t] + ln1b[t];
        h1[t] = fmaxf(y, 0.f);
    }
    __syncthreads();
    if (t < 64) {
        float a2v = 0.f;
        for (int k2 = 0; k2 < 128; k2++) a2v = fmaf(h1[k2], fc2W[k2 * 64 + t], a2v);
        h2[t] = a2v + fc2b[t];
    }
    __syncthreads();
    red[t] = (t < 64) ? h2[t] : 0.f;
    __syncthreads();
    for (int s = 128; s >= 1; s >>= 1) { if (t < s) red[t] += red[t + s]; __syncthreads(); }
    float mean2 = red[0] / 64.f;
    __syncthreads();
    float dv2 = (t < 64) ? (h2[t] - mean2) : 0.f;
    red[t] = dv2 * dv2;
    __syncthreads();
    for (int s = 128; s >= 1; s >>= 1) { if (t < s) red[t] += red[t + s]; __syncthreads(); }
    float var2 = red[0] / 64.f;
    __syncthreads();
    if (t < 64)
        h2[t] = fmaxf((h2[t] - mean2) * rsqrtf(var2 + 1e-5f) * ln2g[t] + ln2b[t], 0.f);
    __syncthreads();
    red[t] = (t < 64) ? h2[t] * fc3W[t] : 0.f;
    __syncthreads();
    for (int s = 128; s >= 1; s >>= 1) { if (t < s) red[t] += red[t + s]; __syncthreads(); }
    if (t == 0) out[b] = 1.f / (1.f + expf(-(red[0] + fc3b[0])));
}

// ---------------------------------------------------------------------------
extern "C" void kernel_launch(void* const* d_in, const int* in_sizes, int n_in,
                              void* d_out, int out_size, void* d_ws, size_t ws_size,
                              hipStream_t stream) {
    const float* x1   = (const float*)d_in[0];
    const float* ew1  = (const float*)d_in[1];
    const float* x2   = (const float*)d_in[2];
    const float* ew2  = (const float*)d_in[3];
    const float* Wg1  = (const float*)d_in[4];
    const float* bg1  = (const float*)d_in[5];
    const float* Wg2  = (const float*)d_in[6];
    const float* bg2  = (const float*)d_in[7];
    const float* fc1W = (const float*)d_in[8];
    const float* fc1b = (const float*)d_in[9];
    const float* ln1g = (const float*)d_in[10];
    const float* ln1b = (const float*)d_in[11];
    const float* fc2W = (const float*)d_in[12];
    const float* fc2b = (const float*)d_in[13];
    const float* ln2g = (const float*)d_in[14];
    const float* ln2b = (const float*)d_in[15];
    const float* fc3W = (const float*)d_in[16];
    const float* fc3b = (const float*)d_in[17];
    const int* ei1    = (const int*)d_in[18];
    const int* ei2    = (const int*)d_in[19];
    float* out = (float*)d_out;

    const int N1 = in_sizes[0] / 128;        // 102400
    const int E1 = in_sizes[1];              // 1638400
    const int N2 = in_sizes[2] / 128;        // 199
    const int E2 = in_sizes[3];              // 3184
    const int B  = out_size;                 // 64
    const int NPG = N1 / B;                  // 1600
    const int K  = (in_sizes[8] / 128) / N2; // 50
    const int PK = K * N2;                   // 9950
    const int NCHUNK = (PK + FC1_CH - 1) / FC1_CH;  // 39
    const int NB1024 = (N1 + 1023) / 1024;   // 100

    char* wsb = (char*)d_ws;
    size_t o = 0;
    auto alloc = [&](size_t bytes) -> void* {
        void* p = wsb + o;
        o += (bytes + 255) & ~(size_t)255;
        return p;
    };
    float* deg1   = (float*)alloc((size_t)N1 * 4);        // becomes dinv1
    int*   cnt    = (int*)alloc((size_t)N1 * 4);
    int*   cur    = (int*)alloc((size_t)N1 * 4);
    int*   off    = (int*)alloc((size_t)(N1 + 1) * 4);
    int*   bsum   = (int*)alloc(128 * 4);
    int*   bscan  = (int*)alloc(128 * 4);
    int2*  packed = (int2*)alloc((size_t)E1 * 8);
    float* z      = (float*)alloc((size_t)N1 * 128 * 4);  // z1, then z2
    float* h      = (float*)alloc((size_t)N1 * 128 * 4);  // h1, then o1
    float* dl     = (float*)alloc((size_t)N1 * 4);
    int*   tki    = (int*)alloc((size_t)B * K * 4);
    float* pooled = (float*)alloc((size_t)B * K * N2 * 4);
    float* h1p    = (float*)alloc((size_t)B * NCHUNK * 128 * 4);
    float* dinv2  = (float*)alloc((size_t)N2 * 4);
    float* z2g    = (float*)alloc((size_t)N2 * 128 * 4);
    float* h2b    = (float*)alloc((size_t)N2 * 128 * 4);
    float* a2a    = (float*)alloc((size_t)N2 * 128 * 4);
    float* zz2    = (float*)alloc((size_t)N2 * 64 * 4);
    float* a2b    = (float*)alloc((size_t)N2 * 64 * 4);
    float* o2b    = (float*)alloc((size_t)N2 * 64 * 4);
    float* s2     = (float*)alloc((size_t)N2 * 4);
    (void)ws_size; (void)n_in;

    const int* src1 = ei1;
    const int* dst1 = ei1 + E1;

    // -------- graph1 CSR build --------
    init1_kernel<<<(N1 + 255) / 256, 256, 0, stream>>>(deg1, cnt, cur, N1);
    hist_kernel<<<(E1 + 255) / 256, 256, 0, stream>>>(dst1, ew1, deg1, cnt, E1);
    rsqrt_kernel<<<(N1 + 255) / 256, 256, 0, stream>>>(deg1, N1);
    scanA_kernel<<<NB1024, 1024, 0, stream>>>(cnt, off, bsum, N1);
    scanB_kernel<<<1, 256, 0, stream>>>(bsum, bscan, NB1024, off, N1);
    scanC_kernel<<<NB1024, 1024, 0, stream>>>(off, bscan, N1);
    csr_kernel<<<(E1 + 255) / 256, 256, 0, stream>>>(dst1, src1, ew1, deg1, off, cur, packed, E1);

    // -------- graph1 layer 1 --------
    gemm_kernel<128><<<N1 / 64, 256, 0, stream>>>(x1, Wg1, z, N1);
    agg_kernel<128, false><<<N1 / 4, 256, 0, stream>>>(z, packed, off, deg1, bg1, h, N1,
                                                       nullptr, nullptr, nullptr, N2);
    gemm_kernel<64><<<N1 / 64, 256, 0, stream>>>(h, Wg2, z, N1);   // z := z2

    // -------- graph2 GNN (needed before fused agg64+dlast) --------
    g2_prep<<<1, 256, 0, stream>>>(ei2, ew2, dinv2, a2a, a2b, E2, N2);
    g2_gemm<128><<<N2, 128, 0, stream>>>(x2, Wg1, z2g, N2);
    g2_scatter<128><<<(E2 + 3) / 4, 256, 0, stream>>>(z2g, ei2, ew2, dinv2, a2a, E2);
    g2_fin128<<<(N2 * 128 + 255) / 256, 256, 0, stream>>>(a2a, z2g, dinv2, bg1, h2b, N2);
    g2_gemm<64><<<N2, 64, 0, stream>>>(h2b, Wg2, zz2, N2);
    g2_scatter<64><<<(E2 + 3) / 4, 256, 0, stream>>>(zz2, ei2, ew2, dinv2, a2b, E2);
    g2_fin64s2<<<(N2 + 3) / 4, 256, 0, stream>>>(a2b, zz2, dinv2, bg2, o2b, s2, N2);

    // -------- graph1 layer 2 agg + fused dlast --------
    agg_kernel<64, true><<<N1 / 4, 256, 0, stream>>>(z, packed, off, deg1, bg2, h, N1,
                                                     o2b, s2, dl, N2);  // h := o1

    // -------- SortAggregation + head --------
    topk_kernel<<<B, 256, 0, stream>>>(dl, tki, NPG, K);
    pooled_kernel<<<B * K, 256, 0, stream>>>(h, o2b, s2, tki, pooled, NPG, K, N2);
    fc1_kernel<<<NCHUNK * B, 256, 0, stream>>>(pooled, fc1W, h1p, PK, NCHUNK, B);
    head2_kernel<<<B, 256, 0, stream>>>(h1p, NCHUNK, fc1b, ln1g, ln1b, fc2W, fc2b,
                                        ln2g, ln2b, fc3W, fc3b, out);
}

// Round 5
// 629.479 us; speedup vs baseline: 1.6962x; 1.0994x over previous
//
#include <hip/hip_runtime.h>
#include <hip/hip_bf16.h>
#include <cstdint>

// ---------------------------------------------------------------------------
// SiameseGNN. R5: (1) hist uses ONE u64 atomic/edge (deg 40-bit fixed-point +
// cnt in high bits); rsqrt/cnt-extract folded into scanA. (2) gemm64 fused
// into agg128 epilogue (wave-local GEMV via LDS h-row) -- h buffer round-trip
// eliminated. Keeps R4: scalar-uniform CSR loop, 4x unroll, packed edge meta,
// fused dlast in agg64, split-K fc1.
// ---------------------------------------------------------------------------

__device__ __forceinline__ int rfl(int v) { return __builtin_amdgcn_readfirstlane(v); }

#define DEG_MASK 0xFFFFFFFFFFull
#define DEG_SCALE 16777216.0f     // 2^24

// ---------------- init: packed = deg 1.0 (self loop), cnt=0; cur=0 ---------
__global__ void init1_kernel(unsigned long long* pdeg, int* cur, int n) {
    int i = blockIdx.x * 256 + threadIdx.x;
    if (i < n) { pdeg[i] = (unsigned long long)(1u << 24); cur[i] = 0; }
}

// ---------------- histogram: one u64 atomic per edge -----------------------
__global__ void hist_kernel(const int* __restrict__ dst, const float* __restrict__ ew,
                            unsigned long long* pdeg, int E) {
    int e = blockIdx.x * 256 + threadIdx.x;
    if (e < E) {
        unsigned long long inc =
            (1ull << 40) | (unsigned long long)__float2uint_rn(ew[e] * DEG_SCALE);
        atomicAdd(&pdeg[dst[e]], inc);
    }
}

// ---------------- scanA: extract cnt -> block scan; dinv = rsqrt(deg) ------
__global__ __launch_bounds__(1024) void scanA_kernel(const unsigned long long* __restrict__ pdeg,
                                                     float* __restrict__ dinv,
                                                     int* __restrict__ off,
                                                     int* __restrict__ bsum, int n) {
    __shared__ int wsum[16], woff[16];
    int t = threadIdx.x, lane = t & 63, wid = t >> 6;
    int i = blockIdx.x * 1024 + t;
    int v = 0;
    if (i < n) {
        unsigned long long p = pdeg[i];
        v = (int)(p >> 40);
        float deg = (float)(p & DEG_MASK) * (1.0f / DEG_SCALE);
        dinv[i] = rsqrtf(deg);
    }
    int s = v;
    for (int d = 1; d < 64; d <<= 1) { int u = __shfl_up(s, d); if (lane >= d) s += u; }
    if (lane == 63) wsum[wid] = s;
    __syncthreads();
    if (t == 0) {
        int run = 0;
        for (int w = 0; w < 16; w++) { int u = wsum[w]; woff[w] = run; run += u; }
        bsum[blockIdx.x] = run;
    }
    __syncthreads();
    if (i < n) off[i] = woff[wid] + s - v;   // block-local exclusive
}

__global__ void scanB_kernel(int* __restrict__ bsum, int* __restrict__ bscan,
                             int nb, int* __restrict__ off, int n) {
    __shared__ int sh[128];
    int t = threadIdx.x;
    if (t < nb) sh[t] = bsum[t];
    __syncthreads();
    if (t == 0) {
        int run = 0;
        for (int j = 0; j < nb; j++) { int u = sh[j]; sh[j] = run; run += u; }
        off[n] = run;
    }
    __syncthreads();
    if (t < nb) bscan[t] = sh[t];
}

__global__ __launch_bounds__(1024) void scanC_kernel(int* __restrict__ off,
                                                     const int* __restrict__ bscan, int n) {
    int i = blockIdx.x * 1024 + threadIdx.x;
    if (i < n) off[i] += bscan[blockIdx.x];
}

// ---------------- CSR placement + packed meta {src, ew*dinv[src]} ----------
__global__ void csr_kernel(const int* __restrict__ dst, const int* __restrict__ src,
                           const float* __restrict__ ew, const float* __restrict__ dinv,
                           const int* __restrict__ off, int* cur,
                           int2* __restrict__ packed, int E) {
    int e = blockIdx.x * 256 + threadIdx.x;
    if (e < E) {
        int d = dst[e];
        int pos = off[d] + atomicAdd(&cur[d], 1);
        int s = src[e];
        packed[pos] = make_int2(s, __float_as_int(ew[e] * dinv[s]));
    }
}

// ---------------- GEMM: [nrows,128] @ [128,NCOL] -> [nrows,NCOL] -----------
template <int NCOL>
__global__ __launch_bounds__(256) void gemm_kernel(const float* __restrict__ x,
                                                   const float* __restrict__ w,
                                                   float* __restrict__ out, int nrows) {
    constexpr int TX = NCOL / 8;
    constexpr int TY = 256 / TX;
    constexpr int AR = 64 / TY;
    __shared__ float ws[64 * NCOL];
    __shared__ float xs[64 * 68];
    int t = threadIdx.x;
    size_t r0 = (size_t)blockIdx.x * 64;
    int tx = t % TX, ty = t / TX;
    float acc[AR][8];
#pragma unroll
    for (int i = 0; i < AR; i++)
#pragma unroll
        for (int j = 0; j < 8; j++) acc[i][j] = 0.f;

    for (int half = 0; half < 2; half++) {
        __syncthreads();
        for (int f = t; f < 64 * NCOL / 4; f += 256)
            ((float4*)ws)[f] = ((const float4*)(w + half * 64 * NCOL))[f];
        for (int f = t; f < 64 * 16; f += 256) {
            int row = f >> 4, c4 = f & 15;
            float4 v = *((const float4*)(x + (r0 + row) * 128 + half * 64 + c4 * 4));
            *((float4*)(xs + row * 68 + c4 * 4)) = v;
        }
        __syncthreads();
        for (int k = 0; k < 64; k++) {
            float4 b0 = *((const float4*)(ws + k * NCOL + tx * 8));
            float4 b1 = *((const float4*)(ws + k * NCOL + tx * 8 + 4));
            float bb[8] = {b0.x, b0.y, b0.z, b0.w, b1.x, b1.y, b1.z, b1.w};
#pragma unroll
            for (int i = 0; i < AR; i++) {
                float a = xs[(ty * AR + i) * 68 + k];
#pragma unroll
                for (int j = 0; j < 8; j++) acc[i][j] = fmaf(a, bb[j], acc[i][j]);
            }
        }
    }
#pragma unroll
    for (int i = 0; i < AR; i++) {
        size_t row = r0 + ty * AR + i;
        float4 v0 = {acc[i][0], acc[i][1], acc[i][2], acc[i][3]};
        float4 v1 = {acc[i][4], acc[i][5], acc[i][6], acc[i][7]};
        *((float4*)(out + row * NCOL + tx * 8)) = v0;
        *((float4*)(out + row * NCOL + tx * 8 + 4)) = v1;
    }
}

// ---------------- CSR aggregation, scalar-uniform edge loop ----------------
// One wave per node. FUSE_GEMM64 (C=128): epilogue computes z2 = relu_row@Wg2
// via wave-local LDS staging (h never hits HBM). FUSE_DLAST (C=64): emits
// dlast = dist(row, o2[N2-1]).
template <int C, bool FUSE_DLAST, bool FUSE_GEMM64>
__global__ __launch_bounds__(256) void agg_kernel(const float* __restrict__ z,
                                                  const int2* __restrict__ packed,
                                                  const int* __restrict__ off,
                                                  const float* __restrict__ dinv,
                                                  const float* __restrict__ bias,
                                                  float* __restrict__ out, int n,
                                                  const float* __restrict__ o2,
                                                  const float* __restrict__ s2,
                                                  float* __restrict__ dlast, int N2,
                                                  const float* __restrict__ w2,
                                                  float* __restrict__ z2out) {
    __shared__ float hrow[4][128];
    int wid = threadIdx.x >> 6;
    int lane = threadIdx.x & 63;
    int d = rfl(blockIdx.x * 4 + wid);
    if (d >= n) return;
    float dv = dinv[d];
    float acc0, acc1 = 0.f;
    float b0, b1 = 0.f;
    if (C == 128) {
        float2 zv = *((const float2*)(z + (size_t)d * C + lane * 2));
        acc0 = dv * zv.x; acc1 = dv * zv.y;
        float2 bv = *((const float2*)(bias + lane * 2));
        b0 = bv.x; b1 = bv.y;
    } else {
        acc0 = dv * z[(size_t)d * C + lane];
        b0 = bias[lane];
    }
    int e0 = off[d], e1 = off[d + 1];
    int e = e0;
    for (; e + 4 <= e1; e += 4) {
        int2 m0 = packed[e], m1 = packed[e + 1], m2 = packed[e + 2], m3 = packed[e + 3];
        int s0 = rfl(m0.x), s1 = rfl(m1.x), s2i = rfl(m2.x), s3 = rfl(m3.x);
        float w0 = __int_as_float(rfl(m0.y)), w1 = __int_as_float(rfl(m1.y));
        float w2v = __int_as_float(rfl(m2.y)), w3 = __int_as_float(rfl(m3.y));
        if (C == 128) {
            float2 v0 = *((const float2*)(z + (size_t)s0 * C + lane * 2));
            float2 v1 = *((const float2*)(z + (size_t)s1 * C + lane * 2));
            float2 v2 = *((const float2*)(z + (size_t)s2i * C + lane * 2));
            float2 v3 = *((const float2*)(z + (size_t)s3 * C + lane * 2));
            acc0 = fmaf(w0, v0.x, acc0); acc1 = fmaf(w0, v0.y, acc1);
            acc0 = fmaf(w1, v1.x, acc0); acc1 = fmaf(w1, v1.y, acc1);
            acc0 = fmaf(w2v, v2.x, acc0); acc1 = fmaf(w2v, v2.y, acc1);
            acc0 = fmaf(w3, v3.x, acc0); acc1 = fmaf(w3, v3.y, acc1);
        } else {
            float v0 = z[(size_t)s0 * C + lane];
            float v1 = z[(size_t)s1 * C + lane];
            float v2 = z[(size_t)s2i * C + lane];
            float v3 = z[(size_t)s3 * C + lane];
            acc0 = fmaf(w0, v0, acc0);
            acc0 = fmaf(w1, v1, acc0);
            acc0 = fmaf(w2v, v2, acc0);
            acc0 = fmaf(w3, v3, acc0);
        }
    }
    for (; e < e1; e++) {
        int2 m = packed[e];
        int s = rfl(m.x);
        float w = __int_as_float(rfl(m.y));
        if (C == 128) {
            float2 v = *((const float2*)(z + (size_t)s * C + lane * 2));
            acc0 = fmaf(w, v.x, acc0); acc1 = fmaf(w, v.y, acc1);
        } else {
            acc0 = fmaf(w, z[(size_t)s * C + lane], acc0);
        }
    }
    if (C == 128) {
        float a0 = fmaxf(dv * acc0 + b0, 0.f);
        float a1 = fmaxf(dv * acc1 + b1, 0.f);
        if (FUSE_GEMM64) {
            // wave-local GEMV: z2[d,:] = hrow @ Wg2 (same FMA order as gemm64)
            hrow[wid][lane * 2] = a0;
            hrow[wid][lane * 2 + 1] = a1;
            float zacc = 0.f;
#pragma unroll 8
            for (int c = 0; c < 128; c++)
                zacc = fmaf(hrow[wid][c], w2[c * 64 + lane], zacc);
            z2out[(size_t)d * 64 + lane] = zacc;
        } else {
            int c = lane * 2;
            float2 ov = {a0, a1};
            *((float2*)(out + (size_t)d * C + c)) = ov;
        }
    } else {
        float a = fmaxf(dv * acc0 + b0, 0.f);
        out[(size_t)d * C + lane] = a;
        if (FUSE_DLAST) {
            float bl = o2[(size_t)(N2 - 1) * 64 + lane];
            float aa = a * a, ab = a * bl;
            for (int dd = 32; dd >= 1; dd >>= 1) {
                aa += __shfl_xor(aa, dd);
                ab += __shfl_xor(ab, dd);
            }
            if (lane == 0) {
                float d2 = aa + s2[N2 - 1] - 2.f * ab;
                dlast[d] = sqrtf(fmaxf(d2, 0.f) + 1e-12f);
            }
        }
    }
}

// ---------------- graph2 (row-major, tiny) ---------------------------------
__global__ void g2_prep(const int* __restrict__ ei2, const float* __restrict__ ew2,
                        float* dinv2, float* a2a, float* a2b, int E2, int N2) {
    __shared__ float degl[256];
    int t = threadIdx.x;
    degl[t] = 1.0f;
    __syncthreads();
    for (int e = t; e < E2; e += 256) atomicAdd(&degl[ei2[E2 + e]], ew2[e]);
    __syncthreads();
    if (t < N2) dinv2[t] = rsqrtf(degl[t]);
    for (int i = t; i < N2 * 128; i += 256) a2a[i] = 0.f;
    for (int i = t; i < N2 * 64; i += 256) a2b[i] = 0.f;
}

template <int NCOL>
__global__ void g2_gemm(const float* __restrict__ x, const float* __restrict__ w,
                        float* __restrict__ z, int N2) {
    __shared__ float xr[128];
    int row = blockIdx.x, t = threadIdx.x;
    for (int k = t; k < 128; k += NCOL) xr[k] = x[row * 128 + k];
    __syncthreads();
    float acc = 0.f;
    for (int k = 0; k < 128; k++) acc = fmaf(xr[k], w[k * NCOL + t], acc);
    z[row * NCOL + t] = acc;
}

template <int C>
__global__ void g2_scatter(const float* __restrict__ z, const int* __restrict__ ei2,
                           const float* __restrict__ ew2, const float* __restrict__ dinv2,
                           float* a2, int E2) {
    constexpr int CPL = C / 64;
    int wid = threadIdx.x >> 6, lane = threadIdx.x & 63;
    int e = blockIdx.x * 4 + wid;
    if (e >= E2) return;
    int s = ei2[e], d = ei2[E2 + e];
    float nm = dinv2[s] * ew2[e] * dinv2[d];
#pragma unroll
    for (int q = 0; q < CPL; q++) {
        int c = lane * CPL + q;
        atomicAdd(&a2[d * C + c], nm * z[s * C + c]);
    }
}

__global__ void g2_fin128(const float* __restrict__ a2, const float* __restrict__ z,
                          const float* __restrict__ dinv2, const float* __restrict__ bias,
                          float* __restrict__ out, int N2) {
    int i = blockIdx.x * 256 + threadIdx.x;
    if (i >= N2 * 128) return;
    int n = i / 128, c = i % 128;
    float dv = dinv2[n];
    out[i] = fmaxf(a2[i] + dv * dv * z[i] + bias[c], 0.f);
}

__global__ void g2_fin64s2(const float* __restrict__ a2, const float* __restrict__ z,
                           const float* __restrict__ dinv2, const float* __restrict__ bias,
                           float* __restrict__ out, float* __restrict__ s2, int N2) {
    int wid = threadIdx.x >> 6, lane = threadIdx.x & 63;
    int row = blockIdx.x * 4 + wid;
    if (row >= N2) return;
    int i = row * 64 + lane;
    float dv = dinv2[row];
    float v = fmaxf(a2[i] + dv * dv * z[i] + bias[lane], 0.f);
    out[i] = v;
    float ss = v * v;
    for (int d = 32; d >= 1; d >>= 1) ss += __shfl_xor(ss, d);
    if (lane == 0) s2[row] = ss;
}

// ---------------- top-K per graph (wave-shfl argmax, stable ties) ----------
__global__ __launch_bounds__(256) void topk_kernel(const float* __restrict__ dlast,
                                                   int* __restrict__ topidx,
                                                   int NPG, int K) {
    __shared__ unsigned long long keys[1600];
    __shared__ unsigned long long wmax[4];
    int g = blockIdx.x, t = threadIdx.x;
    int lane = t & 63, wid = t >> 6;
    for (int r = t; r < NPG; r += 256) {
        unsigned vb = __float_as_uint(dlast[(size_t)g * NPG + r]);  // dist > 0
        keys[r] = ((unsigned long long)vb << 32) | (unsigned)(NPG - 1 - r);
    }
    __syncthreads();
    for (int it = 0; it < K; it++) {
        unsigned long long m = 0ull;
        for (int r = t; r < NPG; r += 256) { unsigned long long k = keys[r]; if (k > m) m = k; }
        for (int d = 32; d >= 1; d >>= 1) {
            unsigned long long u = __shfl_xor(m, d);
            if (u > m) m = u;
        }
        if (lane == 0) wmax[wid] = m;
        __syncthreads();
        if (t == 0) {
            unsigned long long mm = wmax[0];
            for (int w = 1; w < 4; w++) if (wmax[w] > mm) mm = wmax[w];
            int rbest = NPG - 1 - (int)(mm & 0xffffffffull);
            topidx[g * K + it] = rbest;
            keys[rbest] = 0ull;
        }
        __syncthreads();
    }
}

// ---------------- pooled rows: dist(o1[sel], o2[j]) for j<N2 ---------------
__global__ void pooled_kernel(const float* __restrict__ o1, const float* __restrict__ o2,
                              const float* __restrict__ s2, const int* __restrict__ topidx,
                              float* __restrict__ pooled, int NPG, int K, int N2) {
    __shared__ float o1s[64];
    __shared__ float s1sh;
    int g = blockIdx.x / K, kk = blockIdx.x % K;
    int t = threadIdx.x;
    int r = topidx[g * K + kk];
    size_t node = (size_t)g * NPG + r;
    if (t < 64) o1s[t] = o1[node * 64 + t];
    __syncthreads();
    if (t < 64) {
        float v = o1s[t]; float ss = v * v;
        for (int d = 32; d >= 1; d >>= 1) ss += __shfl_xor(ss, d);
        if (t == 0) s1sh = ss;
    }
    __syncthreads();
    if (t < N2) {
        float dot = 0.f;
#pragma unroll 8
        for (int k2 = 0; k2 < 64; k2++) dot = fmaf(o1s[k2], o2[t * 64 + k2], dot);
        float d2 = s1sh + s2[t] - 2.f * dot;
        pooled[(size_t)blockIdx.x * N2 + t] = sqrtf(fmaxf(d2, 0.f) + 1e-12f);
    }
}

// ---------------- fc1 split-K partial GEMM ---------------------------------
#define FC1_CH 256
__global__ __launch_bounds__(256) void fc1_kernel(const float* __restrict__ pooled,
                                                  const float* __restrict__ fc1W,
                                                  float* __restrict__ h1p,
                                                  int PK, int NCHUNK, int B) {
    __shared__ float ps[FC1_CH];
    __shared__ float red[256];
    int b = blockIdx.x % B, ch = blockIdx.x / B;
    int r0 = ch * FC1_CH;
    int nr = min(FC1_CH, PK - r0);
    int t = threadIdx.x;
    for (int i = t; i < nr; i += 256) ps[i] = pooled[(size_t)b * PK + r0 + i];
    __syncthreads();
    int c = t & 127, half = t >> 7;
    int rb = half * (FC1_CH / 2);
    int re = min(rb + FC1_CH / 2, nr);
    float acc = 0.f;
    for (int r = rb; r < re; r++)
        acc = fmaf(ps[r], fc1W[(size_t)(r0 + r) * 128 + c], acc);
    red[t] = acc;
    __syncthreads();
    if (t < 128) h1p[((size_t)b * NCHUNK + ch) * 128 + t] = red[t] + red[t + 128];
}

// ---------------- head tail ------------------------------------------------
__global__ __launch_bounds__(256) void head2_kernel(
    const float* __restrict__ h1p, int NCHUNK,
    const float* __restrict__ fc1b, const float* __restrict__ ln1g,
    const float* __restrict__ ln1b, const float* __restrict__ fc2W,
    const float* __restrict__ fc2b, const float* __restrict__ ln2g,
    const float* __restrict__ ln2b, const float* __restrict__ fc3W,
    const float* __restrict__ fc3b, float* __restrict__ out) {
    __shared__ float red[256];
    __shared__ float h1[128];
    __shared__ float h2[64];
    int b = blockIdx.x, t = threadIdx.x;
    if (t < 128) {
        float s = 0.f;
        for (int ch = 0; ch < NCHUNK; ch++)
            s += h1p[((size_t)b * NCHUNK + ch) * 128 + t];
        h1[t] = s + fc1b[t];
    }
    __syncthreads();
    red[t] = (t < 128) ? h1[t] : 0.f;
    __syncthreads();
    for (int s = 128; s >= 1; s >>= 1) { if (t < s) red[t] += red[t + s]; __syncthreads(); }
    float mean1 = red[0] / 128.f;
    __syncthreads();
    float dv1 = (t < 128) ? (h1[t] - mean1) : 0.f;
    red[t] = dv1 * dv1;
    __syncthreads();
    for (int s = 128; s >= 1; s >>= 1) { if (t < s) red[t] += red[t + s]; __syncthreads(); }
    float var1 = red[0] / 128.f;
    __syncthreads();
    if (t < 128) {
        float y = (h1[t] - mean1) * rsqrtf(var1 + 1e-5f) * ln1g[t] + ln1b[t];
        h1[t] = fmaxf(y, 0.f);
    }
    __syncthreads();
    if (t < 64) {
        float a2v = 0.f;
        for (int k2 = 0; k2 < 128; k2++) a2v = fmaf(h1[k2], fc2W[k2 * 64 + t], a2v);
        h2[t] = a2v + fc2b[t];
    }
    __syncthreads();
    red[t] = (t < 64) ? h2[t] : 0.f;
    __syncthreads();
    for (int s = 128; s >= 1; s >>= 1) { if (t < s) red[t] += red[t + s]; __syncthreads(); }
    float mean2 = red[0] / 64.f;
    __syncthreads();
    float dv2 = (t < 64) ? (h2[t] - mean2) : 0.f;
    red[t] = dv2 * dv2;
    __syncthreads();
    for (int s = 128; s >= 1; s >>= 1) { if (t < s) red[t] += red[t + s]; __syncthreads(); }
    float var2 = red[0] / 64.f;
    __syncthreads();
    if (t < 64)
        h2[t] = fmaxf((h2[t] - mean2) * rsqrtf(var2 + 1e-5f) * ln2g[t] + ln2b[t], 0.f);
    __syncthreads();
    red[t] = (t < 64) ? h2[t] * fc3W[t] : 0.f;
    __syncthreads();
    for (int s = 128; s >= 1; s >>= 1) { if (t < s) red[t] += red[t + s]; __syncthreads(); }
    if (t == 0) out[b] = 1.f / (1.f + expf(-(red[0] + fc3b[0])));
}

// ---------------------------------------------------------------------------
extern "C" void kernel_launch(void* const* d_in, const int* in_sizes, int n_in,
                              void* d_out, int out_size, void* d_ws, size_t ws_size,
                              hipStream_t stream) {
    const float* x1   = (const float*)d_in[0];
    const float* ew1  = (const float*)d_in[1];
    const float* x2   = (const float*)d_in[2];
    const float* ew2  = (const float*)d_in[3];
    const float* Wg1  = (const float*)d_in[4];
    const float* bg1  = (const float*)d_in[5];
    const float* Wg2  = (const float*)d_in[6];
    const float* bg2  = (const float*)d_in[7];
    const float* fc1W = (const float*)d_in[8];
    const float* fc1b = (const float*)d_in[9];
    const float* ln1g = (const float*)d_in[10];
    const float* ln1b = (const float*)d_in[11];
    const float* fc2W = (const float*)d_in[12];
    const float* fc2b = (const float*)d_in[13];
    const float* ln2g = (const float*)d_in[14];
    const float* ln2b = (const float*)d_in[15];
    const float* fc3W = (const float*)d_in[16];
    const float* fc3b = (const float*)d_in[17];
    const int* ei1    = (const int*)d_in[18];
    const int* ei2    = (const int*)d_in[19];
    float* out = (float*)d_out;

    const int N1 = in_sizes[0] / 128;        // 102400
    const int E1 = in_sizes[1];              // 1638400
    const int N2 = in_sizes[2] / 128;        // 199
    const int E2 = in_sizes[3];              // 3184
    const int B  = out_size;                 // 64
    const int NPG = N1 / B;                  // 1600
    const int K  = (in_sizes[8] / 128) / N2; // 50
    const int PK = K * N2;                   // 9950
    const int NCHUNK = (PK + FC1_CH - 1) / FC1_CH;  // 39
    const int NB1024 = (N1 + 1023) / 1024;   // 100

    char* wsb = (char*)d_ws;
    size_t o = 0;
    auto alloc = [&](size_t bytes) -> void* {
        void* p = wsb + o;
        o += (bytes + 255) & ~(size_t)255;
        return p;
    };
    unsigned long long* pdeg = (unsigned long long*)alloc((size_t)N1 * 8);
    float* dinv1  = (float*)alloc((size_t)N1 * 4);
    int*   cur    = (int*)alloc((size_t)N1 * 4);
    int*   off    = (int*)alloc((size_t)(N1 + 1) * 4);
    int*   bsum   = (int*)alloc(128 * 4);
    int*   bscan  = (int*)alloc(128 * 4);
    int2*  packed = (int2*)alloc((size_t)E1 * 8);
    float* z      = (float*)alloc((size_t)N1 * 128 * 4);  // z1, then o1
    float* z2     = (float*)alloc((size_t)N1 * 64 * 4);   // z2 (fused out)
    float* dl     = (float*)alloc((size_t)N1 * 4);
    int*   tki    = (int*)alloc((size_t)B * K * 4);
    float* pooled = (float*)alloc((size_t)B * K * N2 * 4);
    float* h1p    = (float*)alloc((size_t)B * NCHUNK * 128 * 4);
    float* dinv2  = (float*)alloc((size_t)N2 * 4);
    float* z2g    = (float*)alloc((size_t)N2 * 128 * 4);
    float* h2b    = (float*)alloc((size_t)N2 * 128 * 4);
    float* a2a    = (float*)alloc((size_t)N2 * 128 * 4);
    float* zz2    = (float*)alloc((size_t)N2 * 64 * 4);
    float* a2b    = (float*)alloc((size_t)N2 * 64 * 4);
    float* o2b    = (float*)alloc((size_t)N2 * 64 * 4);
    float* s2     = (float*)alloc((size_t)N2 * 4);
    (void)ws_size; (void)n_in;

    const int* src1 = ei1;
    const int* dst1 = ei1 + E1;

    // -------- graph1 CSR build --------
    init1_kernel<<<(N1 + 255) / 256, 256, 0, stream>>>(pdeg, cur, N1);
    hist_kernel<<<(E1 + 255) / 256, 256, 0, stream>>>(dst1, ew1, pdeg, E1);
    scanA_kernel<<<NB1024, 1024, 0, stream>>>(pdeg, dinv1, off, bsum, N1);
    scanB_kernel<<<1, 256, 0, stream>>>(bsum, bscan, NB1024, off, N1);
    scanC_kernel<<<NB1024, 1024, 0, stream>>>(off, bscan, N1);
    csr_kernel<<<(E1 + 255) / 256, 256, 0, stream>>>(dst1, src1, ew1, dinv1, off, cur, packed, E1);

    // -------- graph1 layer 1 (+fused layer-2 GEMM) --------
    gemm_kernel<128><<<N1 / 64, 256, 0, stream>>>(x1, Wg1, z, N1);
    agg_kernel<128, false, true><<<N1 / 4, 256, 0, stream>>>(
        z, packed, off, dinv1, bg1, nullptr, N1, nullptr, nullptr, nullptr, N2, Wg2, z2);

    // -------- graph2 GNN (needed before fused agg64+dlast) --------
    g2_prep<<<1, 256, 0, stream>>>(ei2, ew2, dinv2, a2a, a2b, E2, N2);
    g2_gemm<128><<<N2, 128, 0, stream>>>(x2, Wg1, z2g, N2);
    g2_scatter<128><<<(E2 + 3) / 4, 256, 0, stream>>>(z2g, ei2, ew2, dinv2, a2a, E2);
    g2_fin128<<<(N2 * 128 + 255) / 256, 256, 0, stream>>>(a2a, z2g, dinv2, bg1, h2b, N2);
    g2_gemm<64><<<N2, 64, 0, stream>>>(h2b, Wg2, zz2, N2);
    g2_scatter<64><<<(E2 + 3) / 4, 256, 0, stream>>>(zz2, ei2, ew2, dinv2, a2b, E2);
    g2_fin64s2<<<(N2 + 3) / 4, 256, 0, stream>>>(a2b, zz2, dinv2, bg2, o2b, s2, N2);

    // -------- graph1 layer 2 agg + fused dlast (o1 -> z buffer) --------
    agg_kernel<64, true, false><<<N1 / 4, 256, 0, stream>>>(
        z2, packed, off, dinv1, bg2, z, N1, o2b, s2, dl, N2, nullptr, nullptr);

    // -------- SortAggregation + head --------
    topk_kernel<<<B, 256, 0, stream>>>(dl, tki, NPG, K);
    pooled_kernel<<<B * K, 256, 0, stream>>>(z, o2b, s2, tki, pooled, NPG, K, N2);
    fc1_kernel<<<NCHUNK * B, 256, 0, stream>>>(pooled, fc1W, h1p, PK, NCHUNK, B);
    head2_kernel<<<B, 256, 0, stream>>>(h1p, NCHUNK, fc1b, ln1g, ln1b, fc2W, fc2b,
                                        ln2g, ln2b, fc3W, fc3b, out);
}

// Round 6
// 601.401 us; speedup vs baseline: 1.7753x; 1.0467x over previous
//
#include <hip/hip_runtime.h>
#include <hip/hip_bf16.h>
#include <cstdint>

// ---------------------------------------------------------------------------
// SiameseGNN. R6: (1) z rows stored dinv-prescaled in BF16 (zs = dinv*z):
// gather bytes halve; edge meta is {src, ew} (no dinv dependency).
// (2) histogram sharded 8x by blockIdx&7 (XCD-pinned under round-robin
// dispatch) -> atomic lines stop ping-ponging across XCD L2s.
// Keeps: scalar-uniform CSR loop + 4x unroll, gemm64 fused into agg128
// epilogue, fused dlast, split-K fc1, parallel scan.
// ---------------------------------------------------------------------------

__device__ __forceinline__ int rfl(int v) { return __builtin_amdgcn_readfirstlane(v); }

__device__ __forceinline__ unsigned short f2bf(float f) {
    unsigned u = __float_as_uint(f);
    u = (u + 0x7fffu + ((u >> 16) & 1u)) >> 16;   // RNE
    return (unsigned short)u;
}
__device__ __forceinline__ float bf2f(unsigned short s) {
    return __uint_as_float((unsigned)s << 16);
}

#define DEG_MASK 0xFFFFFFFFFFull
#define DEG_SCALE 16777216.0f     // 2^24

// ---------------- init: zero 8 histogram shards + cur ----------------------
__global__ void init1_kernel(unsigned long long* pdeg8, int* cur, int n) {
    int i = blockIdx.x * 256 + threadIdx.x;
    if (i < 8 * n) pdeg8[i] = 0ull;
    if (i < n) cur[i] = 0;
}

// ---------------- histogram: one u64 atomic/edge into XCD-local shard ------
__global__ void hist_kernel(const int* __restrict__ dst, const float* __restrict__ ew,
                            unsigned long long* pdeg8, int E, int N1) {
    int e = blockIdx.x * 256 + threadIdx.x;
    unsigned long long* my = pdeg8 + (size_t)(blockIdx.x & 7) * N1;
    if (e < E) {
        unsigned long long inc =
            (1ull << 40) | (unsigned long long)__float2uint_rn(ew[e] * DEG_SCALE);
        atomicAdd(&my[dst[e]], inc);
    }
}

// ---------------- scanA: sum shards -> cnt scan; dinv = rsqrt(1+deg) -------
__global__ __launch_bounds__(1024) void scanA_kernel(const unsigned long long* __restrict__ pdeg8,
                                                     float* __restrict__ dinv,
                                                     int* __restrict__ off,
                                                     int* __restrict__ bsum, int n) {
    __shared__ int wsum[16], woff[16];
    int t = threadIdx.x, lane = t & 63, wid = t >> 6;
    int i = blockIdx.x * 1024 + t;
    int v = 0;
    if (i < n) {
        unsigned long long cnts = 0, degs = 0;
#pragma unroll
        for (int c = 0; c < 8; c++) {
            unsigned long long p = pdeg8[(size_t)c * n + i];
            cnts += p >> 40;
            degs += p & DEG_MASK;
        }
        v = (int)cnts;
        float deg = 1.0f + (float)degs * (1.0f / DEG_SCALE);   // +1 self loop
        dinv[i] = rsqrtf(deg);
    }
    int s = v;
    for (int d = 1; d < 64; d <<= 1) { int u = __shfl_up(s, d); if (lane >= d) s += u; }
    if (lane == 63) wsum[wid] = s;
    __syncthreads();
    if (t == 0) {
        int run = 0;
        for (int w = 0; w < 16; w++) { int u = wsum[w]; woff[w] = run; run += u; }
        bsum[blockIdx.x] = run;
    }
    __syncthreads();
    if (i < n) off[i] = woff[wid] + s - v;   // block-local exclusive
}

__global__ void scanB_kernel(int* __restrict__ bsum, int* __restrict__ bscan,
                             int nb, int* __restrict__ off, int n) {
    __shared__ int sh[128];
    int t = threadIdx.x;
    if (t < nb) sh[t] = bsum[t];
    __syncthreads();
    if (t == 0) {
        int run = 0;
        for (int j = 0; j < nb; j++) { int u = sh[j]; sh[j] = run; run += u; }
        off[n] = run;
    }
    __syncthreads();
    if (t < nb) bscan[t] = sh[t];
}

__global__ __launch_bounds__(1024) void scanC_kernel(int* __restrict__ off,
                                                     const int* __restrict__ bscan, int n) {
    int i = blockIdx.x * 1024 + threadIdx.x;
    if (i < n) off[i] += bscan[blockIdx.x];
}

// ---------------- CSR placement + packed meta {src, ew} --------------------
__global__ void csr_kernel(const int* __restrict__ dst, const int* __restrict__ src,
                           const float* __restrict__ ew,
                           const int* __restrict__ off, int* cur,
                           int2* __restrict__ packed, int E) {
    int e = blockIdx.x * 256 + threadIdx.x;
    if (e < E) {
        int d = dst[e];
        int pos = off[d] + atomicAdd(&cur[d], 1);
        packed[pos] = make_int2(src[e], __float_as_int(ew[e]));
    }
}

// ---------------- GEMM128: zs1 = bf16(dinv * (x @ Wg1)) --------------------
__global__ __launch_bounds__(256) void gemm128_kernel(const float* __restrict__ x,
                                                      const float* __restrict__ w,
                                                      const float* __restrict__ dinv,
                                                      unsigned short* __restrict__ outb,
                                                      int nrows) {
    __shared__ float ws[64 * 128];
    __shared__ float xs[64 * 68];
    int t = threadIdx.x;
    size_t r0 = (size_t)blockIdx.x * 64;
    int tx = t % 16, ty = t / 16;     // TX=16, TY=16, AR=4
    float acc[4][8];
#pragma unroll
    for (int i = 0; i < 4; i++)
#pragma unroll
        for (int j = 0; j < 8; j++) acc[i][j] = 0.f;

    for (int half = 0; half < 2; half++) {
        __syncthreads();
        for (int f = t; f < 64 * 32; f += 256)
            ((float4*)ws)[f] = ((const float4*)(w + half * 64 * 128))[f];
        for (int f = t; f < 64 * 16; f += 256) {
            int row = f >> 4, c4 = f & 15;
            float4 v = *((const float4*)(x + (r0 + row) * 128 + half * 64 + c4 * 4));
            *((float4*)(xs + row * 68 + c4 * 4)) = v;
        }
        __syncthreads();
        for (int k = 0; k < 64; k++) {
            float4 b0 = *((const float4*)(ws + k * 128 + tx * 8));
            float4 b1 = *((const float4*)(ws + k * 128 + tx * 8 + 4));
            float bb[8] = {b0.x, b0.y, b0.z, b0.w, b1.x, b1.y, b1.z, b1.w};
#pragma unroll
            for (int i = 0; i < 4; i++) {
                float a = xs[(ty * 4 + i) * 68 + k];
#pragma unroll
                for (int j = 0; j < 8; j++) acc[i][j] = fmaf(a, bb[j], acc[i][j]);
            }
        }
    }
#pragma unroll
    for (int i = 0; i < 4; i++) {
        size_t row = r0 + ty * 4 + i;
        float dv = dinv[row];
        uint4 pk;
        pk.x = (unsigned)f2bf(acc[i][0] * dv) | ((unsigned)f2bf(acc[i][1] * dv) << 16);
        pk.y = (unsigned)f2bf(acc[i][2] * dv) | ((unsigned)f2bf(acc[i][3] * dv) << 16);
        pk.z = (unsigned)f2bf(acc[i][4] * dv) | ((unsigned)f2bf(acc[i][5] * dv) << 16);
        pk.w = (unsigned)f2bf(acc[i][6] * dv) | ((unsigned)f2bf(acc[i][7] * dv) << 16);
        *((uint4*)(outb + row * 128 + tx * 8)) = pk;
    }
}

// ---------------- agg layer1 (bf16 in) + fused gemm64 -> zs2 bf16 ----------
// out = relu(dv*(sum ew*zs[s] + zs[d]) + bg1); zs2 = bf16(dv * (h @ Wg2)).
__global__ __launch_bounds__(256) void agg128_kernel(const unsigned short* __restrict__ zs,
                                                     const int2* __restrict__ packed,
                                                     const int* __restrict__ off,
                                                     const float* __restrict__ dinv,
                                                     const float* __restrict__ bias,
                                                     const float* __restrict__ w2,
                                                     unsigned short* __restrict__ zs2, int n) {
    __shared__ float hrow[4][128];
    int wid = threadIdx.x >> 6;
    int lane = threadIdx.x & 63;
    int d = rfl(blockIdx.x * 4 + wid);
    if (d >= n) return;
    float dv = dinv[d];
    unsigned sv = *((const unsigned*)(zs + (size_t)d * 128 + lane * 2));
    float acc0 = __uint_as_float(sv << 16);
    float acc1 = __uint_as_float(sv & 0xffff0000u);
    float2 bv = *((const float2*)(bias + lane * 2));
    int e0 = off[d], e1 = off[d + 1];
    int e = e0;
    for (; e + 4 <= e1; e += 4) {
        int2 m0 = packed[e], m1 = packed[e + 1], m2 = packed[e + 2], m3 = packed[e + 3];
        int s0 = rfl(m0.x), s1 = rfl(m1.x), s2i = rfl(m2.x), s3 = rfl(m3.x);
        float w0 = __int_as_float(rfl(m0.y)), w1 = __int_as_float(rfl(m1.y));
        float w2v = __int_as_float(rfl(m2.y)), w3 = __int_as_float(rfl(m3.y));
        unsigned v0 = *((const unsigned*)(zs + (size_t)s0 * 128 + lane * 2));
        unsigned v1 = *((const unsigned*)(zs + (size_t)s1 * 128 + lane * 2));
        unsigned v2 = *((const unsigned*)(zs + (size_t)s2i * 128 + lane * 2));
        unsigned v3 = *((const unsigned*)(zs + (size_t)s3 * 128 + lane * 2));
        acc0 = fmaf(w0, __uint_as_float(v0 << 16), acc0);
        acc1 = fmaf(w0, __uint_as_float(v0 & 0xffff0000u), acc1);
        acc0 = fmaf(w1, __uint_as_float(v1 << 16), acc0);
        acc1 = fmaf(w1, __uint_as_float(v1 & 0xffff0000u), acc1);
        acc0 = fmaf(w2v, __uint_as_float(v2 << 16), acc0);
        acc1 = fmaf(w2v, __uint_as_float(v2 & 0xffff0000u), acc1);
        acc0 = fmaf(w3, __uint_as_float(v3 << 16), acc0);
        acc1 = fmaf(w3, __uint_as_float(v3 & 0xffff0000u), acc1);
    }
    for (; e < e1; e++) {
        int2 m = packed[e];
        int s = rfl(m.x);
        float w = __int_as_float(rfl(m.y));
        unsigned v = *((const unsigned*)(zs + (size_t)s * 128 + lane * 2));
        acc0 = fmaf(w, __uint_as_float(v << 16), acc0);
        acc1 = fmaf(w, __uint_as_float(v & 0xffff0000u), acc1);
    }
    float a0 = fmaxf(dv * acc0 + bv.x, 0.f);
    float a1 = fmaxf(dv * acc1 + bv.y, 0.f);
    hrow[wid][lane * 2] = a0;
    hrow[wid][lane * 2 + 1] = a1;
    float zacc = 0.f;
#pragma unroll 8
    for (int c = 0; c < 128; c++)
        zacc = fmaf(hrow[wid][c], w2[c * 64 + lane], zacc);
    zs2[(size_t)d * 64 + lane] = f2bf(dv * zacc);
}

// ---------------- agg layer2 (bf16 in) -> o1 f32 + fused dlast -------------
__global__ __launch_bounds__(256) void agg64_kernel(const unsigned short* __restrict__ zs2,
                                                    const int2* __restrict__ packed,
                                                    const int* __restrict__ off,
                                                    const float* __restrict__ dinv,
                                                    const float* __restrict__ bias,
                                                    float* __restrict__ o1, int n,
                                                    const float* __restrict__ o2,
                                                    const float* __restrict__ s2,
                                                    float* __restrict__ dlast, int N2) {
    int wid = threadIdx.x >> 6;
    int lane = threadIdx.x & 63;
    int d = rfl(blockIdx.x * 4 + wid);
    if (d >= n) return;
    float dv = dinv[d];
    float acc0 = bf2f(zs2[(size_t)d * 64 + lane]);
    float b0 = bias[lane];
    int e0 = off[d], e1 = off[d + 1];
    int e = e0;
    for (; e + 4 <= e1; e += 4) {
        int2 m0 = packed[e], m1 = packed[e + 1], m2 = packed[e + 2], m3 = packed[e + 3];
        int s0 = rfl(m0.x), s1 = rfl(m1.x), s2i = rfl(m2.x), s3 = rfl(m3.x);
        float w0 = __int_as_float(rfl(m0.y)), w1 = __int_as_float(rfl(m1.y));
        float w2v = __int_as_float(rfl(m2.y)), w3 = __int_as_float(rfl(m3.y));
        float v0 = bf2f(zs2[(size_t)s0 * 64 + lane]);
        float v1 = bf2f(zs2[(size_t)s1 * 64 + lane]);
        float v2 = bf2f(zs2[(size_t)s2i * 64 + lane]);
        float v3 = bf2f(zs2[(size_t)s3 * 64 + lane]);
        acc0 = fmaf(w0, v0, acc0);
        acc0 = fmaf(w1, v1, acc0);
        acc0 = fmaf(w2v, v2, acc0);
        acc0 = fmaf(w3, v3, acc0);
    }
    for (; e < e1; e++) {
        int2 m = packed[e];
        int s = rfl(m.x);
        float w = __int_as_float(rfl(m.y));
        acc0 = fmaf(w, bf2f(zs2[(size_t)s * 64 + lane]), acc0);
    }
    float a = fmaxf(dv * acc0 + b0, 0.f);
    o1[(size_t)d * 64 + lane] = a;
    float bl = o2[(size_t)(N2 - 1) * 64 + lane];
    float aa = a * a, ab = a * bl;
    for (int dd = 32; dd >= 1; dd >>= 1) {
        aa += __shfl_xor(aa, dd);
        ab += __shfl_xor(ab, dd);
    }
    if (lane == 0) {
        float d2 = aa + s2[N2 - 1] - 2.f * ab;
        dlast[d] = sqrtf(fmaxf(d2, 0.f) + 1e-12f);
    }
}

// ---------------- graph2 (row-major f32, tiny) -----------------------------
__global__ void g2_prep(const int* __restrict__ ei2, const float* __restrict__ ew2,
                        float* dinv2, float* a2a, float* a2b, int E2, int N2) {
    __shared__ float degl[256];
    int t = threadIdx.x;
    degl[t] = 1.0f;
    __syncthreads();
    for (int e = t; e < E2; e += 256) atomicAdd(&degl[ei2[E2 + e]], ew2[e]);
    __syncthreads();
    if (t < N2) dinv2[t] = rsqrtf(degl[t]);
    for (int i = t; i < N2 * 128; i += 256) a2a[i] = 0.f;
    for (int i = t; i < N2 * 64; i += 256) a2b[i] = 0.f;
}

template <int NCOL>
__global__ void g2_gemm(const float* __restrict__ x, const float* __restrict__ w,
                        float* __restrict__ z, int N2) {
    __shared__ float xr[128];
    int row = blockIdx.x, t = threadIdx.x;
    for (int k = t; k < 128; k += NCOL) xr[k] = x[row * 128 + k];
    __syncthreads();
    float acc = 0.f;
    for (int k = 0; k < 128; k++) acc = fmaf(xr[k], w[k * NCOL + t], acc);
    z[row * NCOL + t] = acc;
}

template <int C>
__global__ void g2_scatter(const float* __restrict__ z, const int* __restrict__ ei2,
                           const float* __restrict__ ew2, const float* __restrict__ dinv2,
                           float* a2, int E2) {
    constexpr int CPL = C / 64;
    int wid = threadIdx.x >> 6, lane = threadIdx.x & 63;
    int e = blockIdx.x * 4 + wid;
    if (e >= E2) return;
    int s = ei2[e], d = ei2[E2 + e];
    float nm = dinv2[s] * ew2[e] * dinv2[d];
#pragma unroll
    for (int q = 0; q < CPL; q++) {
        int c = lane * CPL + q;
        atomicAdd(&a2[d * C + c], nm * z[s * C + c]);
    }
}

__global__ void g2_fin128(const float* __restrict__ a2, const float* __restrict__ z,
                          const float* __restrict__ dinv2, const float* __restrict__ bias,
                          float* __restrict__ out, int N2) {
    int i = blockIdx.x * 256 + threadIdx.x;
    if (i >= N2 * 128) return;
    int n = i / 128, c = i % 128;
    float dv = dinv2[n];
    out[i] = fmaxf(a2[i] + dv * dv * z[i] + bias[c], 0.f);
}

__global__ void g2_fin64s2(const float* __restrict__ a2, const float* __restrict__ z,
                           const float* __restrict__ dinv2, const float* __restrict__ bias,
                           float* __restrict__ out, float* __restrict__ s2, int N2) {
    int wid = threadIdx.x >> 6, lane = threadIdx.x & 63;
    int row = blockIdx.x * 4 + wid;
    if (row >= N2) return;
    int i = row * 64 + lane;
    float dv = dinv2[row];
    float v = fmaxf(a2[i] + dv * dv * z[i] + bias[lane], 0.f);
    out[i] = v;
    float ss = v * v;
    for (int d = 32; d >= 1; d >>= 1) ss += __shfl_xor(ss, d);
    if (lane == 0) s2[row] = ss;
}

// ---------------- top-K per graph (wave-shfl argmax, stable ties) ----------
__global__ __launch_bounds__(256) void topk_kernel(const float* __restrict__ dlast,
                                                   int* __restrict__ topidx,
                                                   int NPG, int K) {
    __shared__ unsigned long long keys[1600];
    __shared__ unsigned long long wmax[4];
    int g = blockIdx.x, t = threadIdx.x;
    int lane = t & 63, wid = t >> 6;
    for (int r = t; r < NPG; r += 256) {
        unsigned vb = __float_as_uint(dlast[(size_t)g * NPG + r]);  // dist > 0
        keys[r] = ((unsigned long long)vb << 32) | (unsigned)(NPG - 1 - r);
    }
    __syncthreads();
    for (int it = 0; it < K; it++) {
        unsigned long long m = 0ull;
        for (int r = t; r < NPG; r += 256) { unsigned long long k = keys[r]; if (k > m) m = k; }
        for (int d = 32; d >= 1; d >>= 1) {
            unsigned long long u = __shfl_xor(m, d);
            if (u > m) m = u;
        }
        if (lane == 0) wmax[wid] = m;
        __syncthreads();
        if (t == 0) {
            unsigned long long mm = wmax[0];
            for (int w = 1; w < 4; w++) if (wmax[w] > mm) mm = wmax[w];
            int rbest = NPG - 1 - (int)(mm & 0xffffffffull);
            topidx[g * K + it] = rbest;
            keys[rbest] = 0ull;
        }
        __syncthreads();
    }
}

// ---------------- pooled rows: dist(o1[sel], o2[j]) for j<N2 ---------------
__global__ void pooled_kernel(const float* __restrict__ o1, const float* __restrict__ o2,
                              const float* __restrict__ s2, const int* __restrict__ topidx,
                              float* __restrict__ pooled, int NPG, int K, int N2) {
    __shared__ float o1s[64];
    __shared__ float s1sh;
    int g = blockIdx.x / K, kk = blockIdx.x % K;
    int t = threadIdx.x;
    int r = topidx[g * K + kk];
    size_t node = (size_t)g * NPG + r;
    if (t < 64) o1s[t] = o1[node * 64 + t];
    __syncthreads();
    if (t < 64) {
        float v = o1s[t]; float ss = v * v;
        for (int d = 32; d >= 1; d >>= 1) ss += __shfl_xor(ss, d);
        if (t == 0) s1sh = ss;
    }
    __syncthreads();
    if (t < N2) {
        float dot = 0.f;
#pragma unroll 8
        for (int k2 = 0; k2 < 64; k2++) dot = fmaf(o1s[k2], o2[t * 64 + k2], dot);
        float d2 = s1sh + s2[t] - 2.f * dot;
        pooled[(size_t)blockIdx.x * N2 + t] = sqrtf(fmaxf(d2, 0.f) + 1e-12f);
    }
}

// ---------------- fc1 split-K partial GEMM ---------------------------------
#define FC1_CH 256
__global__ __launch_bounds__(256) void fc1_kernel(const float* __restrict__ pooled,
                                                  const float* __restrict__ fc1W,
                                                  float* __restrict__ h1p,
                                                  int PK, int NCHUNK, int B) {
    __shared__ float ps[FC1_CH];
    __shared__ float red[256];
    int b = blockIdx.x % B, ch = blockIdx.x / B;
    int r0 = ch * FC1_CH;
    int nr = min(FC1_CH, PK - r0);
    int t = threadIdx.x;
    for (int i = t; i < nr; i += 256) ps[i] = pooled[(size_t)b * PK + r0 + i];
    __syncthreads();
    int c = t & 127, half = t >> 7;
    int rb = half * (FC1_CH / 2);
    int re = min(rb + FC1_CH / 2, nr);
    float acc = 0.f;
    for (int r = rb; r < re; r++)
        acc = fmaf(ps[r], fc1W[(size_t)(r0 + r) * 128 + c], acc);
    red[t] = acc;
    __syncthreads();
    if (t < 128) h1p[((size_t)b * NCHUNK + ch) * 128 + t] = red[t] + red[t + 128];
}

// ---------------- head tail ------------------------------------------------
__global__ __launch_bounds__(256) void head2_kernel(
    const float* __restrict__ h1p, int NCHUNK,
    const float* __restrict__ fc1b, const float* __restrict__ ln1g,
    const float* __restrict__ ln1b, const float* __restrict__ fc2W,
    const float* __restrict__ fc2b, const float* __restrict__ ln2g,
    const float* __restrict__ ln2b, const float* __restrict__ fc3W,
    const float* __restrict__ fc3b, float* __restrict__ out) {
    __shared__ float red[256];
    __shared__ float h1[128];
    __shared__ float h2[64];
    int b = blockIdx.x, t = threadIdx.x;
    if (t < 128) {
        float s = 0.f;
        for (int ch = 0; ch < NCHUNK; ch++)
            s += h1p[((size_t)b * NCHUNK + ch) * 128 + t];
        h1[t] = s + fc1b[t];
    }
    __syncthreads();
    red[t] = (t < 128) ? h1[t] : 0.f;
    __syncthreads();
    for (int s = 128; s >= 1; s >>= 1) { if (t < s) red[t] += red[t + s]; __syncthreads(); }
    float mean1 = red[0] / 128.f;
    __syncthreads();
    float dv1 = (t < 128) ? (h1[t] - mean1) : 0.f;
    red[t] = dv1 * dv1;
    __syncthreads();
    for (int s = 128; s >= 1; s >>= 1) { if (t < s) red[t] += red[t + s]; __syncthreads(); }
    float var1 = red[0] / 128.f;
    __syncthreads();
    if (t < 128) {
        float y = (h1[t] - mean1) * rsqrtf(var1 + 1e-5f) * ln1g[t] + ln1b[t];
        h1[t] = fmaxf(y, 0.f);
    }
    __syncthreads();
    if (t < 64) {
        float a2v = 0.f;
        for (int k2 = 0; k2 < 128; k2++) a2v = fmaf(h1[k2], fc2W[k2 * 64 + t], a2v);
        h2[t] = a2v + fc2b[t];
    }
    __syncthreads();
    red[t] = (t < 64) ? h2[t] : 0.f;
    __syncthreads();
    for (int s = 128; s >= 1; s >>= 1) { if (t < s) red[t] += red[t + s]; __syncthreads(); }
    float mean2 = red[0] / 64.f;
    __syncthreads();
    float dv2 = (t < 64) ? (h2[t] - mean2) : 0.f;
    red[t] = dv2 * dv2;
    __syncthreads();
    for (int s = 128; s >= 1; s >>= 1) { if (t < s) red[t] += red[t + s]; __syncthreads(); }
    float var2 = red[0] / 64.f;
    __syncthreads();
    if (t < 64)
        h2[t] = fmaxf((h2[t] - mean2) * rsqrtf(var2 + 1e-5f) * ln2g[t] + ln2b[t], 0.f);
    __syncthreads();
    red[t] = (t < 64) ? h2[t] * fc3W[t] : 0.f;
    __syncthreads();
    for (int s = 128; s >= 1; s >>= 1) { if (t < s) red[t] += red[t + s]; __syncthreads(); }
    if (t == 0) out[b] = 1.f / (1.f + expf(-(red[0] + fc3b[0])));
}

// ---------------------------------------------------------------------------
extern "C" void kernel_launch(void* const* d_in, const int* in_sizes, int n_in,
                              void* d_out, int out_size, void* d_ws, size_t ws_size,
                              hipStream_t stream) {
    const float* x1   = (const float*)d_in[0];
    const float* ew1  = (const float*)d_in[1];
    const float* x2   = (const float*)d_in[2];
    const float* ew2  = (const float*)d_in[3];
    const float* Wg1  = (const float*)d_in[4];
    const float* bg1  = (const float*)d_in[5];
    const float* Wg2  = (const float*)d_in[6];
    const float* bg2  = (const float*)d_in[7];
    const float* fc1W = (const float*)d_in[8];
    const float* fc1b = (const float*)d_in[9];
    const float* ln1g = (const float*)d_in[10];
    const float* ln1b = (const float*)d_in[11];
    const float* fc2W = (const float*)d_in[12];
    const float* fc2b = (const float*)d_in[13];
    const float* ln2g = (const float*)d_in[14];
    const float* ln2b = (const float*)d_in[15];
    const float* fc3W = (const float*)d_in[16];
    const float* fc3b = (const float*)d_in[17];
    const int* ei1    = (const int*)d_in[18];
    const int* ei2    = (const int*)d_in[19];
    float* out = (float*)d_out;

    const int N1 = in_sizes[0] / 128;        // 102400
    const int E1 = in_sizes[1];              // 1638400
    const int N2 = in_sizes[2] / 128;        // 199
    const int E2 = in_sizes[3];              // 3184
    const int B  = out_size;                 // 64
    const int NPG = N1 / B;                  // 1600
    const int K  = (in_sizes[8] / 128) / N2; // 50
    const int PK = K * N2;                   // 9950
    const int NCHUNK = (PK + FC1_CH - 1) / FC1_CH;  // 39
    const int NB1024 = (N1 + 1023) / 1024;   // 100

    char* wsb = (char*)d_ws;
    size_t o = 0;
    auto alloc = [&](size_t bytes) -> void* {
        void* p = wsb + o;
        o += (bytes + 255) & ~(size_t)255;
        return p;
    };
    unsigned long long* pdeg8 = (unsigned long long*)alloc((size_t)N1 * 8 * 8);
    float* dinv1  = (float*)alloc((size_t)N1 * 4);
    int*   cur    = (int*)alloc((size_t)N1 * 4);
    int*   off    = (int*)alloc((size_t)(N1 + 1) * 4);
    int*   bsum   = (int*)alloc(128 * 4);
    int*   bscan  = (int*)alloc(128 * 4);
    int2*  packed = (int2*)alloc((size_t)E1 * 8);
    unsigned short* zs1 = (unsigned short*)alloc((size_t)N1 * 128 * 2);
    unsigned short* zs2 = (unsigned short*)alloc((size_t)N1 * 64 * 2);
    float* o1buf  = (float*)alloc((size_t)N1 * 64 * 4);
    float* dl     = (float*)alloc((size_t)N1 * 4);
    int*   tki    = (int*)alloc((size_t)B * K * 4);
    float* pooled = (float*)alloc((size_t)B * K * N2 * 4);
    float* h1p    = (float*)alloc((size_t)B * NCHUNK * 128 * 4);
    float* dinv2  = (float*)alloc((size_t)N2 * 4);
    float* z2g    = (float*)alloc((size_t)N2 * 128 * 4);
    float* h2b    = (float*)alloc((size_t)N2 * 128 * 4);
    float* a2a    = (float*)alloc((size_t)N2 * 128 * 4);
    float* zz2    = (float*)alloc((size_t)N2 * 64 * 4);
    float* a2b    = (float*)alloc((size_t)N2 * 64 * 4);
    float* o2b    = (float*)alloc((size_t)N2 * 64 * 4);
    float* s2     = (float*)alloc((size_t)N2 * 4);
    (void)ws_size; (void)n_in;

    const int* src1 = ei1;
    const int* dst1 = ei1 + E1;

    // -------- graph1 CSR build --------
    init1_kernel<<<(8 * N1 + 255) / 256, 256, 0, stream>>>(pdeg8, cur, N1);
    hist_kernel<<<(E1 + 255) / 256, 256, 0, stream>>>(dst1, ew1, pdeg8, E1, N1);
    scanA_kernel<<<NB1024, 1024, 0, stream>>>(pdeg8, dinv1, off, bsum, N1);
    scanB_kernel<<<1, 256, 0, stream>>>(bsum, bscan, NB1024, off, N1);
    scanC_kernel<<<NB1024, 1024, 0, stream>>>(off, bscan, N1);
    csr_kernel<<<(E1 + 255) / 256, 256, 0, stream>>>(dst1, src1, ew1, off, cur, packed, E1);

    // -------- graph1 layer 1 (+fused layer-2 GEMM) --------
    gemm128_kernel<<<N1 / 64, 256, 0, stream>>>(x1, Wg1, dinv1, zs1, N1);
    agg128_kernel<<<N1 / 4, 256, 0, stream>>>(zs1, packed, off, dinv1, bg1, Wg2, zs2, N1);

    // -------- graph2 GNN (needed before fused agg64+dlast) --------
    g2_prep<<<1, 256, 0, stream>>>(ei2, ew2, dinv2, a2a, a2b, E2, N2);
    g2_gemm<128><<<N2, 128, 0, stream>>>(x2, Wg1, z2g, N2);
    g2_scatter<128><<<(E2 + 3) / 4, 256, 0, stream>>>(z2g, ei2, ew2, dinv2, a2a, E2);
    g2_fin128<<<(N2 * 128 + 255) / 256, 256, 0, stream>>>(a2a, z2g, dinv2, bg1, h2b, N2);
    g2_gemm<64><<<N2, 64, 0, stream>>>(h2b, Wg2, zz2, N2);
    g2_scatter<64><<<(E2 + 3) / 4, 256, 0, stream>>>(zz2, ei2, ew2, dinv2, a2b, E2);
    g2_fin64s2<<<(N2 + 3) / 4, 256, 0, stream>>>(a2b, zz2, dinv2, bg2, o2b, s2, N2);

    // -------- graph1 layer 2 agg + fused dlast --------
    agg64_kernel<<<N1 / 4, 256, 0, stream>>>(zs2, packed, off, dinv1, bg2, o1buf, N1,
                                             o2b, s2, dl, N2);

    // -------- SortAggregation + head --------
    topk_kernel<<<B, 256, 0, stream>>>(dl, tki, NPG, K);
    pooled_kernel<<<B * K, 256, 0, stream>>>(o1buf, o2b, s2, tki, pooled, NPG, K, N2);
    fc1_kernel<<<NCHUNK * B, 256, 0, stream>>>(pooled, fc1W, h1p, PK, NCHUNK, B);
    head2_kernel<<<B, 256, 0, stream>>>(h1p, NCHUNK, fc1b, ln1g, ln1b, fc2W, fc2b,
                                        ln2g, ln2b, fc3W, fc3b, out);
}